// Round 9
// baseline (752.902 us; speedup 1.0000x reference)
//
#include <hip/hip_runtime.h>
#include <cmath>

#define SEQ 1600
#define NB  1024
#define H   12
#define PP  8

// ---- param block offsets (floats) in workspace ----
#define O_G0   0      // 8 x float4
#define O_H0   32
#define O_G1   64
#define O_G2   96
#define O_H12  128
#define O_C0V  160    // 48 x float4
#define O_C1V  352
#define O_BB1  544
#define O_BB2  736
#define O_F0   928    // 12 x float4
#define O_F1   976
#define O_CW   1024   // 8 x float2
#define O_A6   1040   // 24 x float2
#define O_A7   1088
#define O_SC   1136   // 2 floats
#define PRMF   1138

// r0 buffer: [b][j][q][tid] float4 planes, j<7, q<3, tid<256  (fully coalesced)
__device__ __forceinline__ size_t r0base(int b, int j, int tid) {
    return (((size_t)b * 7 + j) * 3) * 256 + tid;
}

// ---------------- BN stats ----------------
__global__ __launch_bounds__(256) void k_stats1(const float* __restrict__ x,
                                                float* __restrict__ pS,
                                                float* __restrict__ pQ) {
    int l = blockIdx.x * 256 + threadIdx.x;
    if (l >= SEQ) return;
    int b0 = blockIdx.y * 64;
    float s = 0.f, q = 0.f;
    for (int b = 0; b < 64; ++b) {
        float v = x[(size_t)(b0 + b) * SEQ + l];
        s += v; q += v * v;
    }
    pS[blockIdx.y * SEQ + l] = s;
    pQ[blockIdx.y * SEQ + l] = q;
}

__global__ __launch_bounds__(256) void k_stats2(const float* __restrict__ pS,
                                                const float* __restrict__ pQ,
                                                const float* __restrict__ w1,
                                                const float* __restrict__ b1,
                                                const float* __restrict__ gam,
                                                const float* __restrict__ bet,
                                                float* __restrict__ scale,
                                                float* __restrict__ shift) {
    int l = blockIdx.x * 256 + threadIdx.x;
    if (l >= SEQ) return;
    float wm = 0, wq = 0, wb = 0, bm = 0, bq = 0;
    for (int h = 0; h < H; h++) {
        float w = w1[h], b = b1[h];
        wm += w; wq += w * w; wb += w * b; bm += b; bq += b * b;
    }
    const float inv = 1.f / 12.f;
    wm *= inv; wq *= inv; wb *= inv; bm *= inv; bq *= inv;
    float s = 0, q = 0;
    for (int k = 0; k < 16; k++) { s += pS[k * SEQ + l]; q += pQ[k * SEQ + l]; }
    float ex = s * (1.f / NB), exx = q * (1.f / NB);
    float mean = ex * wm + bm;
    float e2   = exx * wq + 2.f * ex * wb + bq;
    float var  = e2 - mean * mean;
    float sc   = gam[l] * rsqrtf(var + 1e-5f);
    scale[l] = sc;
    shift[l] = bet[l] - mean * sc;
}

// ---------------- one-time derived parameters ----------------
__global__ void k_prep(const float* __restrict__ l1w, const float* __restrict__ l1b,
                       const float* __restrict__ l2w, const float* __restrict__ l2b,
                       const float* __restrict__ lamr, const float* __restrict__ lami,
                       const float* __restrict__ bre, const float* __restrict__ bim,
                       const float* __restrict__ cre, const float* __restrict__ cim,
                       const float* __restrict__ dv,  const float* __restrict__ lstep,
                       float* __restrict__ gprm) {
    const int t = threadIdx.x;
    if (t < 48) {   // C matrices layers 0,1 as float4 (re,im,re,im)
        int h = t >> 2, k = t & 3, p0 = 2 * k, p1 = 2 * k + 1;
        gprm[O_C0V + 4 * t + 0] = cre[h * PP + p0];
        gprm[O_C0V + 4 * t + 1] = cim[h * PP + p0];
        gprm[O_C0V + 4 * t + 2] = cre[h * PP + p1];
        gprm[O_C0V + 4 * t + 3] = cim[h * PP + p1];
        gprm[O_C1V + 4 * t + 0] = cre[96 + h * PP + p0];
        gprm[O_C1V + 4 * t + 1] = cim[96 + h * PP + p0];
        gprm[O_C1V + 4 * t + 2] = cre[96 + h * PP + p1];
        gprm[O_C1V + 4 * t + 3] = cim[96 + h * PP + p1];
    }
    if (t < H) {
        float w = l1w[t], bb = l1b[t];
        float d0 = dv[t], d1 = dv[H + t], d2 = dv[2 * H + t];
        gprm[O_F0 + 4 * t + 0] = w * d0;
        gprm[O_F0 + 4 * t + 1] = bb * d0;
        gprm[O_F0 + 4 * t + 2] = d0;
        gprm[O_F0 + 4 * t + 3] = w * d1;
        gprm[O_F1 + 4 * t + 0] = bb * d1;
        gprm[O_F1 + 4 * t + 1] = d1;
        gprm[O_F1 + 4 * t + 2] = l2w[t] * d2;
        gprm[O_F1 + 4 * t + 3] = 0.f;
    }
    if (t == 0) {
        float s0 = l2b[0], s1 = 0.f;
        for (int h = 0; h < H; h++) {
            float dw = l2w[h] * dv[2 * H + h];
            s0 += l1b[h] * dw; s1 += l1w[h] * dw;
        }
        gprm[O_SC + 0] = s0; gprm[O_SC + 1] = s1;
    }
    if (t < 24) {
        int L = t >> 3, p = t & 7;
        float stp = expf(lstep[L * PP + p]);
        float lr = lamr[L * PP + p], li = lami[L * PP + p];
        float er = expf(lr * stp);
        float lbr = er * cosf(li * stp), lbi = er * sinf(li * stp);   // lam_bar
        float p2r = lbr * lbr - lbi * lbi, p2i = 2.f * lbr * lbi;
        float p4r = p2r * p2r - p2i * p2i, p4i = 2.f * p2r * p2i;
        float p6r = p4r * p2r - p4i * p2i, p6i = p4r * p2i + p4i * p2r;
        float p7r = p6r * lbr - p6i * lbi, p7i = p6r * lbi + p6i * lbr;
        gprm[O_A6 + 2 * (L * PP + p) + 0] = p6r;
        gprm[O_A6 + 2 * (L * PP + p) + 1] = p6i;
        gprm[O_A7 + 2 * (L * PP + p) + 0] = p7r;
        gprm[O_A7 + 2 * (L * PP + p) + 1] = p7i;
        float den = lr * lr + li * li;
        float fr = ((lbr - 1.f) * lr + lbi * li) / den;
        float fi = (lbi * lr - (lbr - 1.f) * li) / den;
        float sAr = 0, sAi = 0, sBr = 0, sBi = 0, sCr = 0, sCi = 0;
        for (int h = 0; h < H; h++) {
            float brr = bre[L * 96 + p * H + h], bii = bim[L * 96 + p * H + h];
            float vr = fr * brr - fi * bii, vi = fr * bii + fi * brr;  // b_bar[p,h]
            float w = l1w[h], bb = l1b[h];
            sAr += w * vr; sAi += w * vi; sBr += bb * vr; sBi += bb * vi; sCr += vr; sCi += vi;
            int fidx = h * 16 + (p >> 1) * 4 + (p & 1) * 2;
            if (L == 1)      { gprm[O_BB1 + fidx] = vr; gprm[O_BB1 + fidx + 1] = vi; }
            else if (L == 2) { gprm[O_BB2 + fidx] = vr; gprm[O_BB2 + fidx + 1] = vi; }
        }
        if (L == 0) {
            gprm[O_G0 + 4 * p + 0] = sAr; gprm[O_G0 + 4 * p + 1] = sAi;
            gprm[O_G0 + 4 * p + 2] = sBr; gprm[O_G0 + 4 * p + 3] = sBi;
            gprm[O_H0 + 4 * p + 0] = sCr; gprm[O_H0 + 4 * p + 1] = sCi;
            gprm[O_H0 + 4 * p + 2] = lbr; gprm[O_H0 + 4 * p + 3] = lbi;
        } else if (L == 1) {
            gprm[O_G1 + 4 * p + 0] = sAr; gprm[O_G1 + 4 * p + 1] = sAi;
            gprm[O_G1 + 4 * p + 2] = sBr; gprm[O_G1 + 4 * p + 3] = sBi;
            gprm[O_H12 + 4 * p + 0] = lbr; gprm[O_H12 + 4 * p + 1] = lbi;
        } else {
            gprm[O_G2 + 4 * p + 0] = sAr; gprm[O_G2 + 4 * p + 1] = sAi;
            gprm[O_G2 + 4 * p + 2] = sBr; gprm[O_G2 + 4 * p + 3] = sBi;
            gprm[O_H12 + 4 * p + 2] = lbr; gprm[O_H12 + 4 * p + 3] = lbi;
            float swr = 0, swi = 0;
            for (int hh = 0; hh < H; hh++) {
                float wv = l2w[hh];
                swr += wv * cre[192 + hh * PP + p];
                swi += wv * cim[192 + hh * PP + p];
            }
            gprm[O_CW + 2 * p + 0] = swr; gprm[O_CW + 2 * p + 1] = swi;
        }
    }
}

// ---- hierarchical carry scan across 256 threads (4 waves x 64 lanes) ----
__device__ __forceinline__ void scan_carry256(float* Sr, float* Si,
                                              const float2* a_init,
                                              int lane, int w,
                                              float2 (*aggA)[PP], float2 (*aggS)[PP]) {
    float Ar[PP], Ai[PP];
#pragma unroll
    for (int p = 0; p < PP; p++) { float2 a = a_init[p]; Ar[p] = a.x; Ai[p] = a.y; }
#pragma unroll
    for (int d = 1; d < 64; d <<= 1) {
#pragma unroll
        for (int p = 0; p < PP; p++) {
            float fSr = __shfl_up(Sr[p], (unsigned)d, 64);
            float fSi = __shfl_up(Si[p], (unsigned)d, 64);
            float fAr = __shfl_up(Ar[p], (unsigned)d, 64);
            float fAi = __shfl_up(Ai[p], (unsigned)d, 64);
            if (lane >= d) {
                float nsr = Ar[p] * fSr - Ai[p] * fSi + Sr[p];
                float nsi = Ar[p] * fSi + Ai[p] * fSr + Si[p];
                float nar = fAr * Ar[p] - fAi * Ai[p];
                float nai = fAr * Ai[p] + fAi * Ar[p];
                Sr[p] = nsr; Si[p] = nsi; Ar[p] = nar; Ai[p] = nai;
            }
        }
    }
    __syncthreads();   // protect agg buffer from previous use
    if (lane == 63) {
#pragma unroll
        for (int p = 0; p < PP; p++) {
            aggA[w][p] = make_float2(Ar[p], Ai[p]);
            aggS[w][p] = make_float2(Sr[p], Si[p]);
        }
    }
    __syncthreads();
    float eSr[PP], eSi[PP], eAr[PP], eAi[PP];
#pragma unroll
    for (int p = 0; p < PP; p++) {
        float sr = __shfl_up(Sr[p], 1u, 64);
        float si = __shfl_up(Si[p], 1u, 64);
        float ar = __shfl_up(Ar[p], 1u, 64);
        float ai = __shfl_up(Ai[p], 1u, 64);
        eSr[p] = (lane > 0) ? sr : 0.f;
        eSi[p] = (lane > 0) ? si : 0.f;
        eAr[p] = (lane > 0) ? ar : 1.f;
        eAi[p] = (lane > 0) ? ai : 0.f;
    }
    float Pr[PP], Pi[PP];
#pragma unroll
    for (int p = 0; p < PP; p++) { Pr[p] = 0.f; Pi[p] = 0.f; }
    for (int w2 = 0; w2 < w; w2++) {
#pragma unroll
        for (int p = 0; p < PP; p++) {
            float2 a = aggA[w2][p];
            float2 s = aggS[w2][p];
            float nr = a.x * Pr[p] - a.y * Pi[p] + s.x;
            float ni = a.x * Pi[p] + a.y * Pr[p] + s.y;
            Pr[p] = nr; Pi[p] = ni;
        }
    }
#pragma unroll
    for (int p = 0; p < PP; p++) {
        Sr[p] = eAr[p] * Pr[p] - eAi[p] * Pi[p] + eSr[p];
        Si[p] = eAr[p] * Pi[p] + eAi[p] * Pr[p] + eSi[p];
    }
}

// ---------------- layer 0: BN-folded scan, writes r0 (coalesced layout) ----------------
__global__ __launch_bounds__(256)
void k_l0(const float* __restrict__ x,
          const float* __restrict__ gprm,
          const float* __restrict__ g_scale, const float* __restrict__ g_shift,
          float* __restrict__ r0buf) {
    __shared__ __align__(16) float prm[PRMF];
    __shared__ float xl[SEQ], scl[SEQ], shl[SEQ];
    __shared__ float2 aggA[4][PP], aggS[4][PP];
    const int tid = threadIdx.x, b = blockIdx.x;
    for (int i = tid; i < PRMF; i += 256) prm[i] = gprm[i];
    for (int i = tid; i < SEQ; i += 256) {
        xl[i] = x[(size_t)b * SEQ + i];
        scl[i] = g_scale[i];
        shl[i] = g_shift[i];
    }
    __syncthreads();
    const float4* g0v = (const float4*)(prm + O_G0);
    const float4* h0v = (const float4*)(prm + O_H0);
    const float4* c0v = (const float4*)(prm + O_C0V);
    const float4* f0v = (const float4*)(prm + O_F0);
    const int w = tid >> 6, lane = tid & 63;
    const int len = (w == 3) ? 7 : 6;
    const int l0 = (w < 3) ? (w * 384 + lane * 6) : (1152 + lane * 7);
    const float2* aL0 = (const float2*)(prm + ((w == 3) ? O_A7 : O_A6));

    float s0r[PP], s0i[PP];
#pragma unroll
    for (int p = 0; p < PP; p++) { s0r[p] = 0.f; s0i[p] = 0.f; }
#pragma unroll 1
    for (int j = 0; j < len; j++) {
        int l = l0 + j;
        float xx = xl[l], sc = scl[l], sh = shl[l];
        float xs = xx * sc;
#pragma unroll
        for (int p = 0; p < PP; p++) {
            float4 g = g0v[p]; float4 hv = h0v[p];
            float bur = xs * g.x + sc * g.z + sh * hv.x;
            float bui = xs * g.y + sc * g.w + sh * hv.y;
            float nr = hv.z * s0r[p] - hv.w * s0i[p] + bur;
            float ni = hv.z * s0i[p] + hv.w * s0r[p] + bui;
            s0r[p] = nr; s0i[p] = ni;
        }
    }
    scan_carry256(s0r, s0i, aL0, lane, w, aggA, aggS);
    float4* r0q = (float4*)r0buf;
#pragma unroll 1
    for (int j = 0; j < len; j++) {
        int l = l0 + j;
        float xx = xl[l], sc = scl[l], sh = shl[l];
        float xs = xx * sc;
#pragma unroll
        for (int p = 0; p < PP; p++) {
            float4 g = g0v[p]; float4 hv = h0v[p];
            float bur = xs * g.x + sc * g.z + sh * hv.x;
            float bui = xs * g.y + sc * g.w + sh * hv.y;
            float nr = hv.z * s0r[p] - hv.w * s0i[p] + bur;
            float ni = hv.z * s0i[p] + hv.w * s0r[p] + bui;
            s0r[p] = nr; s0i[p] = ni;
        }
        float r0v[H];
#pragma unroll
        for (int h = 0; h < H; h++) {
            float acc = 0.f;
#pragma unroll
            for (int k = 0; k < 4; k++) {
                float4 v = c0v[h * 4 + k];
                acc += s0r[2 * k] * v.x - s0i[2 * k] * v.y + s0r[2 * k + 1] * v.z - s0i[2 * k + 1] * v.w;
            }
            float4 f = f0v[h];
            float y0 = 2.f * acc + xs * f.x + sc * f.y + sh * f.z;
            r0v[h] = fmaxf(y0, 0.f);
        }
        size_t base = r0base(b, j, tid);
        r0q[base]       = make_float4(r0v[0], r0v[1], r0v[2], r0v[3]);
        r0q[base + 256] = make_float4(r0v[4], r0v[5], r0v[6], r0v[7]);
        r0q[base + 512] = make_float4(r0v[8], r0v[9], r0v[10], r0v[11]);
    }
}

// ---------------- layers 1+2 fused: 2-pass over r0, rs stays in registers ----------------
__global__ __launch_bounds__(256)
void k_l12(const float* __restrict__ x,
           const float* __restrict__ gprm,
           const float* __restrict__ r0buf,
           float* __restrict__ out) {
    __shared__ __align__(16) float prm[PRMF];
    __shared__ float xl[SEQ];
    __shared__ float po[SEQ];
    __shared__ float2 aggA[4][PP], aggS[4][PP];
    const int tid = threadIdx.x, b = blockIdx.x;
    for (int i = tid; i < PRMF; i += 256) prm[i] = gprm[i];
    for (int i = tid; i < SEQ; i += 256) xl[i] = x[(size_t)b * SEQ + i];
    __syncthreads();
    const float4* g1v  = (const float4*)(prm + O_G1);
    const float4* g2v  = (const float4*)(prm + O_G2);
    const float4* h12v = (const float4*)(prm + O_H12);
    const float4* c1v  = (const float4*)(prm + O_C1V);
    const float4* bb1  = (const float4*)(prm + O_BB1);
    const float4* bb2  = (const float4*)(prm + O_BB2);
    const float4* f0v  = (const float4*)(prm + O_F0);
    const float4* f1v  = (const float4*)(prm + O_F1);
    const float2* cwv  = (const float2*)(prm + O_CW);
    const float Sc0 = prm[O_SC], Sc1 = prm[O_SC + 1];
    const int w = tid >> 6, lane = tid & 63;
    const int len = (w == 3) ? 7 : 6;
    const int l0 = (w < 3) ? (w * 384 + lane * 6) : (1152 + lane * 7);
    const float2* aL1 = (const float2*)(prm + ((w == 3) ? O_A7 : O_A6)) + 1 * PP;
    const float2* aL2 = (const float2*)(prm + ((w == 3) ? O_A7 : O_A6)) + 2 * PP;
    const float4* r0q = (const float4*)r0buf;

    float s1r[PP], s1i[PP];
#pragma unroll
    for (int p = 0; p < PP; p++) { s1r[p] = 0.f; s1i[p] = 0.f; }

    // ---- pass 1: layer-1 local scan (prefetched r0) ----
    float4 nra, nrb, nrc;
    {
        size_t base = r0base(b, 0, tid);
        nra = r0q[base]; nrb = r0q[base + 256]; nrc = r0q[base + 512];
    }
#pragma unroll 1
    for (int j = 0; j < len; j++) {
        float4 ra = nra, rb = nrb, rc = nrc;
        if (j + 1 < len) {
            size_t base = r0base(b, j + 1, tid);
            nra = r0q[base]; nrb = r0q[base + 256]; nrc = r0q[base + 512];
        }
        float xx = xl[l0 + j];
        float r0v[H] = {ra.x, ra.y, ra.z, ra.w, rb.x, rb.y, rb.z, rb.w, rc.x, rc.y, rc.z, rc.w};
        float t1r[PP], t1i[PP];
#pragma unroll
        for (int p = 0; p < PP; p++) {
            float4 g = g1v[p];
            t1r[p] = xx * g.x + g.z; t1i[p] = xx * g.y + g.w;
        }
#pragma unroll
        for (int h = 0; h < H; h++) {
            float rh = r0v[h];
#pragma unroll
            for (int k = 0; k < 4; k++) {
                float4 v = bb1[h * 4 + k];
                t1r[2 * k] += rh * v.x; t1i[2 * k] += rh * v.y;
                t1r[2 * k + 1] += rh * v.z; t1i[2 * k + 1] += rh * v.w;
            }
        }
#pragma unroll
        for (int p = 0; p < PP; p++) {
            float4 hv = h12v[p];
            float nr = hv.x * s1r[p] - hv.y * s1i[p] + t1r[p];
            float ni = hv.x * s1i[p] + hv.y * s1r[p] + t1i[p];
            s1r[p] = nr; s1i[p] = ni;
        }
    }
    scan_carry256(s1r, s1i, aL1, lane, w, aggA, aggS);

    // ---- pass 2: layer-1 exact + layer-2 local + partial out (rs in regs only) ----
    float s2r[PP], s2i[PP];
#pragma unroll
    for (int p = 0; p < PP; p++) { s2r[p] = 0.f; s2i[p] = 0.f; }
    {
        size_t base = r0base(b, 0, tid);
        nra = r0q[base]; nrb = r0q[base + 256]; nrc = r0q[base + 512];
    }
#pragma unroll 1
    for (int j = 0; j < len; j++) {
        int l = l0 + j;
        float4 ra = nra, rb = nrb, rc = nrc;
        if (j + 1 < len) {
            size_t base = r0base(b, j + 1, tid);
            nra = r0q[base]; nrb = r0q[base + 256]; nrc = r0q[base + 512];
        }
        float xx = xl[l];
        float r0v[H] = {ra.x, ra.y, ra.z, ra.w, rb.x, rb.y, rb.z, rb.w, rc.x, rc.y, rc.z, rc.w};
        float t1r[PP], t1i[PP];
#pragma unroll
        for (int p = 0; p < PP; p++) {
            float4 g = g1v[p];
            t1r[p] = xx * g.x + g.z; t1i[p] = xx * g.y + g.w;
        }
#pragma unroll
        for (int h = 0; h < H; h++) {
            float rh = r0v[h];
#pragma unroll
            for (int k = 0; k < 4; k++) {
                float4 v = bb1[h * 4 + k];
                t1r[2 * k] += rh * v.x; t1i[2 * k] += rh * v.y;
                t1r[2 * k + 1] += rh * v.z; t1i[2 * k + 1] += rh * v.w;
            }
        }
#pragma unroll
        for (int p = 0; p < PP; p++) {
            float4 hv = h12v[p];
            float nr = hv.x * s1r[p] - hv.y * s1i[p] + t1r[p];
            float ni = hv.x * s1i[p] + hv.y * s1r[p] + t1i[p];
            s1r[p] = nr; s1i[p] = ni;
        }
        // layer-2 local recurrence consuming rs = r0 + relu(y1) directly from regs
        float t2r[PP], t2i[PP];
#pragma unroll
        for (int p = 0; p < PP; p++) {
            float4 g = g2v[p];
            t2r[p] = xx * g.x + g.z; t2i[p] = xx * g.y + g.w;
        }
        float o = Sc0 + xx * Sc1;
#pragma unroll
        for (int h = 0; h < H; h++) {
            float acc = 0.f;
#pragma unroll
            for (int k = 0; k < 4; k++) {
                float4 v = c1v[h * 4 + k];
                acc += s1r[2 * k] * v.x - s1i[2 * k] * v.y + s1r[2 * k + 1] * v.z - s1i[2 * k + 1] * v.w;
            }
            float4 f = f1v[h];
            float y1 = 2.f * acc + r0v[h] * f.y + xx * f0v[h].w + f.x;
            float rs = r0v[h] + fmaxf(y1, 0.f);
            o += rs * f.z;
#pragma unroll
            for (int k = 0; k < 4; k++) {
                float4 v = bb2[h * 4 + k];
                t2r[2 * k] += rs * v.x; t2i[2 * k] += rs * v.y;
                t2r[2 * k + 1] += rs * v.z; t2i[2 * k + 1] += rs * v.w;
            }
        }
#pragma unroll
        for (int p = 0; p < PP; p++) {
            float4 hv = h12v[p];
            float nr = hv.z * s2r[p] - hv.w * s2i[p] + t2r[p];
            float ni = hv.z * s2i[p] + hv.w * s2r[p] + t2i[p];
            s2r[p] = nr; s2i[p] = ni;
        }
        float acc2 = 0.f;
#pragma unroll
        for (int p = 0; p < PP; p++) {
            float2 c = cwv[p];
            acc2 += s2r[p] * c.x - s2i[p] * c.y;
        }
        po[l] = o + 2.f * acc2;   // partial (zero layer-2 carry)
    }
    scan_carry256(s2r, s2i, aL2, lane, w, aggA, aggS);  // -> carry2

    // fixup: += 2*Re(lam2^{j+1} * carry2 . cw)
    float tr[PP], ti_[PP], mr[PP], mi_[PP];
#pragma unroll
    for (int p = 0; p < PP; p++) {
        float2 c = cwv[p];
        tr[p]  = c.x * s2r[p] - c.y * s2i[p];
        ti_[p] = c.x * s2i[p] + c.y * s2r[p];
        float4 hv = h12v[p];
        mr[p] = hv.z; mi_[p] = hv.w;
    }
#pragma unroll 1
    for (int j = 0; j < len; j++) {
        float corr = 0.f;
#pragma unroll
        for (int p = 0; p < PP; p++) corr += mr[p] * tr[p] - mi_[p] * ti_[p];
        po[l0 + j] += 2.f * corr;
#pragma unroll
        for (int p = 0; p < PP; p++) {
            float4 hv = h12v[p];
            float t = mr[p] * hv.z - mi_[p] * hv.w;
            mi_[p] = mr[p] * hv.w + mi_[p] * hv.z;
            mr[p] = t;
        }
    }
    __syncthreads();
    float* orow = out + (size_t)b * SEQ;
    for (int i = tid; i < SEQ; i += 256) orow[i] = po[i];
}

extern "C" void kernel_launch(void* const* d_in, const int* in_sizes, int n_in,
                              void* d_out, int out_size, void* d_ws, size_t ws_size,
                              hipStream_t stream) {
    const float* x     = (const float*)d_in[0];
    const float* l1w   = (const float*)d_in[1];
    const float* l1b   = (const float*)d_in[2];
    const float* l2w   = (const float*)d_in[3];
    const float* l2b   = (const float*)d_in[4];
    const float* gam   = (const float*)d_in[5];
    const float* bet   = (const float*)d_in[6];
    const float* lamr  = (const float*)d_in[7];
    const float* lami  = (const float*)d_in[8];
    const float* bre   = (const float*)d_in[9];
    const float* bim   = (const float*)d_in[10];
    const float* cre   = (const float*)d_in[11];
    const float* cim   = (const float*)d_in[12];
    const float* dv    = (const float*)d_in[13];
    const float* lstep = (const float*)d_in[14];
    float* out = (float*)d_out;

    float* wsf     = (float*)d_ws;
    float* w_scale = wsf;                  // 1600
    float* w_shift = wsf + SEQ;            // 1600
    float* pS      = wsf + 2 * SEQ;        // 16*1600
    float* pQ      = pS + 16 * SEQ;        // 16*1600
    float* gprm    = pQ + 16 * SEQ;        // PRMF (padded to 1280)
    float* r0buf   = gprm + 1280;          // 1024*7*3*256 float4 = 88 MB

    k_prep<<<dim3(1), 64, 0, stream>>>(l1w, l1b, l2w, l2b, lamr, lami,
                                       bre, bim, cre, cim, dv, lstep, gprm);
    k_stats1<<<dim3(7, 16), 256, 0, stream>>>(x, pS, pQ);
    k_stats2<<<dim3(7), 256, 0, stream>>>(pS, pQ, l1w, l1b, gam, bet, w_scale, w_shift);
    k_l0<<<dim3(NB), 256, 0, stream>>>(x, gprm, w_scale, w_shift, r0buf);
    k_l12<<<dim3(NB), 256, 0, stream>>>(x, gprm, r0buf, out);
}

// Round 10
// 401.677 us; speedup vs baseline: 1.8744x; 1.8744x over previous
//
#include <hip/hip_runtime.h>
#include <cmath>

#define SEQ 1600
#define NB  1024
#define H   12
#define PP  8

// ---- param block offsets (floats) in workspace ----
#define O_G0   0      // 8 x float4
#define O_H0   32
#define O_G1   64
#define O_G2   96
#define O_H12  128
#define O_C0V  160    // 48 x float4
#define O_C1V  352
#define O_BB1  544
#define O_BB2  736
#define O_F0   928    // 12 x float4
#define O_F1   976
#define O_CW   1024   // 8 x float2
#define O_A6   1040   // 24 x float2
#define O_A7   1088
#define O_SC   1136   // 2 floats
#define PRMF   1138

// r0 buffer: [b][j][q][tid] float4 planes, j<7, q<3, tid<256  (fully coalesced)
__device__ __forceinline__ size_t r0base(int b, int j, int tid) {
    return (((size_t)b * 7 + j) * 3) * 256 + tid;
}

// ---------------- BN stats ----------------
__global__ __launch_bounds__(256) void k_stats1(const float* __restrict__ x,
                                                float* __restrict__ pS,
                                                float* __restrict__ pQ) {
    int l = blockIdx.x * 256 + threadIdx.x;
    if (l >= SEQ) return;
    int b0 = blockIdx.y * 64;
    float s = 0.f, q = 0.f;
    for (int b = 0; b < 64; ++b) {
        float v = x[(size_t)(b0 + b) * SEQ + l];
        s += v; q += v * v;
    }
    pS[blockIdx.y * SEQ + l] = s;
    pQ[blockIdx.y * SEQ + l] = q;
}

__global__ __launch_bounds__(256) void k_stats2(const float* __restrict__ pS,
                                                const float* __restrict__ pQ,
                                                const float* __restrict__ w1,
                                                const float* __restrict__ b1,
                                                const float* __restrict__ gam,
                                                const float* __restrict__ bet,
                                                float* __restrict__ scale,
                                                float* __restrict__ shift) {
    int l = blockIdx.x * 256 + threadIdx.x;
    if (l >= SEQ) return;
    float wm = 0, wq = 0, wb = 0, bm = 0, bq = 0;
    for (int h = 0; h < H; h++) {
        float w = w1[h], b = b1[h];
        wm += w; wq += w * w; wb += w * b; bm += b; bq += b * b;
    }
    const float inv = 1.f / 12.f;
    wm *= inv; wq *= inv; wb *= inv; bm *= inv; bq *= inv;
    float s = 0, q = 0;
    for (int k = 0; k < 16; k++) { s += pS[k * SEQ + l]; q += pQ[k * SEQ + l]; }
    float ex = s * (1.f / NB), exx = q * (1.f / NB);
    float mean = ex * wm + bm;
    float e2   = exx * wq + 2.f * ex * wb + bq;
    float var  = e2 - mean * mean;
    float sc   = gam[l] * rsqrtf(var + 1e-5f);
    scale[l] = sc;
    shift[l] = bet[l] - mean * sc;
}

// ---------------- one-time derived parameters ----------------
__global__ void k_prep(const float* __restrict__ l1w, const float* __restrict__ l1b,
                       const float* __restrict__ l2w, const float* __restrict__ l2b,
                       const float* __restrict__ lamr, const float* __restrict__ lami,
                       const float* __restrict__ bre, const float* __restrict__ bim,
                       const float* __restrict__ cre, const float* __restrict__ cim,
                       const float* __restrict__ dv,  const float* __restrict__ lstep,
                       float* __restrict__ gprm) {
    const int t = threadIdx.x;
    if (t < 48) {   // C matrices layers 0,1 as float4 (re,im,re,im)
        int h = t >> 2, k = t & 3, p0 = 2 * k, p1 = 2 * k + 1;
        gprm[O_C0V + 4 * t + 0] = cre[h * PP + p0];
        gprm[O_C0V + 4 * t + 1] = cim[h * PP + p0];
        gprm[O_C0V + 4 * t + 2] = cre[h * PP + p1];
        gprm[O_C0V + 4 * t + 3] = cim[h * PP + p1];
        gprm[O_C1V + 4 * t + 0] = cre[96 + h * PP + p0];
        gprm[O_C1V + 4 * t + 1] = cim[96 + h * PP + p0];
        gprm[O_C1V + 4 * t + 2] = cre[96 + h * PP + p1];
        gprm[O_C1V + 4 * t + 3] = cim[96 + h * PP + p1];
    }
    if (t < H) {
        float w = l1w[t], bb = l1b[t];
        float d0 = dv[t], d1 = dv[H + t], d2 = dv[2 * H + t];
        gprm[O_F0 + 4 * t + 0] = w * d0;
        gprm[O_F0 + 4 * t + 1] = bb * d0;
        gprm[O_F0 + 4 * t + 2] = d0;
        gprm[O_F0 + 4 * t + 3] = w * d1;
        gprm[O_F1 + 4 * t + 0] = bb * d1;
        gprm[O_F1 + 4 * t + 1] = d1;
        gprm[O_F1 + 4 * t + 2] = l2w[t] * d2;
        gprm[O_F1 + 4 * t + 3] = 0.f;
    }
    if (t == 0) {
        float s0 = l2b[0], s1 = 0.f;
        for (int h = 0; h < H; h++) {
            float dw = l2w[h] * dv[2 * H + h];
            s0 += l1b[h] * dw; s1 += l1w[h] * dw;
        }
        gprm[O_SC + 0] = s0; gprm[O_SC + 1] = s1;
    }
    if (t < 24) {
        int L = t >> 3, p = t & 7;
        float stp = expf(lstep[L * PP + p]);
        float lr = lamr[L * PP + p], li = lami[L * PP + p];
        float er = expf(lr * stp);
        float lbr = er * cosf(li * stp), lbi = er * sinf(li * stp);   // lam_bar
        float p2r = lbr * lbr - lbi * lbi, p2i = 2.f * lbr * lbi;
        float p4r = p2r * p2r - p2i * p2i, p4i = 2.f * p2r * p2i;
        float p6r = p4r * p2r - p4i * p2i, p6i = p4r * p2i + p4i * p2r;
        float p7r = p6r * lbr - p6i * lbi, p7i = p6r * lbi + p6i * lbr;
        gprm[O_A6 + 2 * (L * PP + p) + 0] = p6r;
        gprm[O_A6 + 2 * (L * PP + p) + 1] = p6i;
        gprm[O_A7 + 2 * (L * PP + p) + 0] = p7r;
        gprm[O_A7 + 2 * (L * PP + p) + 1] = p7i;
        float den = lr * lr + li * li;
        float fr = ((lbr - 1.f) * lr + lbi * li) / den;
        float fi = (lbi * lr - (lbr - 1.f) * li) / den;
        float sAr = 0, sAi = 0, sBr = 0, sBi = 0, sCr = 0, sCi = 0;
        for (int h = 0; h < H; h++) {
            float brr = bre[L * 96 + p * H + h], bii = bim[L * 96 + p * H + h];
            float vr = fr * brr - fi * bii, vi = fr * bii + fi * brr;  // b_bar[p,h]
            float w = l1w[h], bb = l1b[h];
            sAr += w * vr; sAi += w * vi; sBr += bb * vr; sBi += bb * vi; sCr += vr; sCi += vi;
            int fidx = h * 16 + (p >> 1) * 4 + (p & 1) * 2;
            if (L == 1)      { gprm[O_BB1 + fidx] = vr; gprm[O_BB1 + fidx + 1] = vi; }
            else if (L == 2) { gprm[O_BB2 + fidx] = vr; gprm[O_BB2 + fidx + 1] = vi; }
        }
        if (L == 0) {
            gprm[O_G0 + 4 * p + 0] = sAr; gprm[O_G0 + 4 * p + 1] = sAi;
            gprm[O_G0 + 4 * p + 2] = sBr; gprm[O_G0 + 4 * p + 3] = sBi;
            gprm[O_H0 + 4 * p + 0] = sCr; gprm[O_H0 + 4 * p + 1] = sCi;
            gprm[O_H0 + 4 * p + 2] = lbr; gprm[O_H0 + 4 * p + 3] = lbi;
        } else if (L == 1) {
            gprm[O_G1 + 4 * p + 0] = sAr; gprm[O_G1 + 4 * p + 1] = sAi;
            gprm[O_G1 + 4 * p + 2] = sBr; gprm[O_G1 + 4 * p + 3] = sBi;
            gprm[O_H12 + 4 * p + 0] = lbr; gprm[O_H12 + 4 * p + 1] = lbi;
        } else {
            gprm[O_G2 + 4 * p + 0] = sAr; gprm[O_G2 + 4 * p + 1] = sAi;
            gprm[O_G2 + 4 * p + 2] = sBr; gprm[O_G2 + 4 * p + 3] = sBi;
            gprm[O_H12 + 4 * p + 2] = lbr; gprm[O_H12 + 4 * p + 3] = lbi;
            float swr = 0, swi = 0;
            for (int hh = 0; hh < H; hh++) {
                float wv = l2w[hh];
                swr += wv * cre[192 + hh * PP + p];
                swi += wv * cim[192 + hh * PP + p];
            }
            gprm[O_CW + 2 * p + 0] = swr; gprm[O_CW + 2 * p + 1] = swi;
        }
    }
}

// ---- hierarchical carry scan across 256 threads (4 waves x 64 lanes) ----
__device__ __forceinline__ void scan_carry256(float* Sr, float* Si,
                                              const float2* a_init,
                                              int lane, int w,
                                              float2 (*aggA)[PP], float2 (*aggS)[PP]) {
    float Ar[PP], Ai[PP];
#pragma unroll
    for (int p = 0; p < PP; p++) { float2 a = a_init[p]; Ar[p] = a.x; Ai[p] = a.y; }
#pragma unroll
    for (int d = 1; d < 64; d <<= 1) {
#pragma unroll
        for (int p = 0; p < PP; p++) {
            float fSr = __shfl_up(Sr[p], (unsigned)d, 64);
            float fSi = __shfl_up(Si[p], (unsigned)d, 64);
            float fAr = __shfl_up(Ar[p], (unsigned)d, 64);
            float fAi = __shfl_up(Ai[p], (unsigned)d, 64);
            if (lane >= d) {
                float nsr = Ar[p] * fSr - Ai[p] * fSi + Sr[p];
                float nsi = Ar[p] * fSi + Ai[p] * fSr + Si[p];
                float nar = fAr * Ar[p] - fAi * Ai[p];
                float nai = fAr * Ai[p] + fAi * Ar[p];
                Sr[p] = nsr; Si[p] = nsi; Ar[p] = nar; Ai[p] = nai;
            }
        }
    }
    __syncthreads();   // protect agg buffer from previous use
    if (lane == 63) {
#pragma unroll
        for (int p = 0; p < PP; p++) {
            aggA[w][p] = make_float2(Ar[p], Ai[p]);
            aggS[w][p] = make_float2(Sr[p], Si[p]);
        }
    }
    __syncthreads();
    float eSr[PP], eSi[PP], eAr[PP], eAi[PP];
#pragma unroll
    for (int p = 0; p < PP; p++) {
        float sr = __shfl_up(Sr[p], 1u, 64);
        float si = __shfl_up(Si[p], 1u, 64);
        float ar = __shfl_up(Ar[p], 1u, 64);
        float ai = __shfl_up(Ai[p], 1u, 64);
        eSr[p] = (lane > 0) ? sr : 0.f;
        eSi[p] = (lane > 0) ? si : 0.f;
        eAr[p] = (lane > 0) ? ar : 1.f;
        eAi[p] = (lane > 0) ? ai : 0.f;
    }
    float Pr[PP], Pi[PP];
#pragma unroll
    for (int p = 0; p < PP; p++) { Pr[p] = 0.f; Pi[p] = 0.f; }
    for (int w2 = 0; w2 < w; w2++) {
#pragma unroll
        for (int p = 0; p < PP; p++) {
            float2 a = aggA[w2][p];
            float2 s = aggS[w2][p];
            float nr = a.x * Pr[p] - a.y * Pi[p] + s.x;
            float ni = a.x * Pi[p] + a.y * Pr[p] + s.y;
            Pr[p] = nr; Pi[p] = ni;
        }
    }
#pragma unroll
    for (int p = 0; p < PP; p++) {
        Sr[p] = eAr[p] * Pr[p] - eAi[p] * Pi[p] + eSr[p];
        Si[p] = eAr[p] * Pi[p] + eAi[p] * Pr[p] + eSi[p];
    }
}

// ---------------- layer 0: BN-folded scan, writes r0 (coalesced layout) ----------------
// Params read directly from global (wave-uniform -> scalar loads via K$).
__global__ __launch_bounds__(256)
void k_l0(const float* __restrict__ x,
          const float* __restrict__ gprm,
          const float* __restrict__ g_scale, const float* __restrict__ g_shift,
          float* __restrict__ r0buf) {
    __shared__ float xl[SEQ], scl[SEQ], shl[SEQ];
    __shared__ float2 aggA[4][PP], aggS[4][PP];
    const int tid = threadIdx.x, b = blockIdx.x;
    for (int i = tid; i < SEQ; i += 256) {
        xl[i] = x[(size_t)b * SEQ + i];
        scl[i] = g_scale[i];
        shl[i] = g_shift[i];
    }
    __syncthreads();
    const float4* g0v = (const float4*)(gprm + O_G0);
    const float4* h0v = (const float4*)(gprm + O_H0);
    const float4* c0v = (const float4*)(gprm + O_C0V);
    const float4* f0v = (const float4*)(gprm + O_F0);
    const int w = tid >> 6, lane = tid & 63;
    const int len = (w == 3) ? 7 : 6;
    const int l0 = (w < 3) ? (w * 384 + lane * 6) : (1152 + lane * 7);
    const float2* aL0 = (const float2*)(gprm + ((w == 3) ? O_A7 : O_A6));

    float s0r[PP], s0i[PP];
#pragma unroll
    for (int p = 0; p < PP; p++) { s0r[p] = 0.f; s0i[p] = 0.f; }
#pragma unroll 1
    for (int j = 0; j < len; j++) {
        int l = l0 + j;
        float xx = xl[l], sc = scl[l], sh = shl[l];
        float xs = xx * sc;
#pragma unroll
        for (int p = 0; p < PP; p++) {
            float4 g = g0v[p]; float4 hv = h0v[p];
            float bur = xs * g.x + sc * g.z + sh * hv.x;
            float bui = xs * g.y + sc * g.w + sh * hv.y;
            float nr = hv.z * s0r[p] - hv.w * s0i[p] + bur;
            float ni = hv.z * s0i[p] + hv.w * s0r[p] + bui;
            s0r[p] = nr; s0i[p] = ni;
        }
    }
    scan_carry256(s0r, s0i, aL0, lane, w, aggA, aggS);
    float4* r0q = (float4*)r0buf;
#pragma unroll 1
    for (int j = 0; j < len; j++) {
        int l = l0 + j;
        float xx = xl[l], sc = scl[l], sh = shl[l];
        float xs = xx * sc;
#pragma unroll
        for (int p = 0; p < PP; p++) {
            float4 g = g0v[p]; float4 hv = h0v[p];
            float bur = xs * g.x + sc * g.z + sh * hv.x;
            float bui = xs * g.y + sc * g.w + sh * hv.y;
            float nr = hv.z * s0r[p] - hv.w * s0i[p] + bur;
            float ni = hv.z * s0i[p] + hv.w * s0r[p] + bui;
            s0r[p] = nr; s0i[p] = ni;
        }
        float r0v[H];
#pragma unroll
        for (int h = 0; h < H; h++) {
            float acc = 0.f;
#pragma unroll
            for (int k = 0; k < 4; k++) {
                float4 v = c0v[h * 4 + k];
                acc += s0r[2 * k] * v.x - s0i[2 * k] * v.y + s0r[2 * k + 1] * v.z - s0i[2 * k + 1] * v.w;
            }
            float4 f = f0v[h];
            float y0 = 2.f * acc + xs * f.x + sc * f.y + sh * f.z;
            r0v[h] = fmaxf(y0, 0.f);
        }
        size_t base = r0base(b, j, tid);
        r0q[base]       = make_float4(r0v[0], r0v[1], r0v[2], r0v[3]);
        r0q[base + 256] = make_float4(r0v[4], r0v[5], r0v[6], r0v[7]);
        r0q[base + 512] = make_float4(r0v[8], r0v[9], r0v[10], r0v[11]);
    }
}

// ---------------- layer 1: 2-pass over r0 (coalesced), rs written in place ----------------
__global__ __launch_bounds__(256)
void k_l1(const float* __restrict__ x,
          const float* __restrict__ gprm,
          float* __restrict__ r0buf) {
    __shared__ float xl[SEQ];
    __shared__ float2 aggA[4][PP], aggS[4][PP];
    const int tid = threadIdx.x, b = blockIdx.x;
    for (int i = tid; i < SEQ; i += 256) xl[i] = x[(size_t)b * SEQ + i];
    __syncthreads();
    const float4* g1v  = (const float4*)(gprm + O_G1);
    const float4* h12v = (const float4*)(gprm + O_H12);
    const float4* c1v  = (const float4*)(gprm + O_C1V);
    const float4* bb1  = (const float4*)(gprm + O_BB1);
    const float4* f0v  = (const float4*)(gprm + O_F0);
    const float4* f1v  = (const float4*)(gprm + O_F1);
    const int w = tid >> 6, lane = tid & 63;
    const int len = (w == 3) ? 7 : 6;
    const int l0 = (w < 3) ? (w * 384 + lane * 6) : (1152 + lane * 7);
    const float2* aL1 = (const float2*)(gprm + ((w == 3) ? O_A7 : O_A6)) + 1 * PP;
    float4* r0q = (float4*)r0buf;

    float s1r[PP], s1i[PP];
#pragma unroll
    for (int p = 0; p < PP; p++) { s1r[p] = 0.f; s1i[p] = 0.f; }
#pragma unroll 1
    for (int j = 0; j < len; j++) {
        int l = l0 + j;
        float xx = xl[l];
        size_t base = r0base(b, j, tid);
        float4 ra = r0q[base], rb = r0q[base + 256], rc = r0q[base + 512];
        float r0v[H] = {ra.x, ra.y, ra.z, ra.w, rb.x, rb.y, rb.z, rb.w, rc.x, rc.y, rc.z, rc.w};
        float t1r[PP], t1i[PP];
#pragma unroll
        for (int p = 0; p < PP; p++) {
            float4 g = g1v[p];
            t1r[p] = xx * g.x + g.z; t1i[p] = xx * g.y + g.w;
        }
#pragma unroll
        for (int h = 0; h < H; h++) {
            float rh = r0v[h];
#pragma unroll
            for (int k = 0; k < 4; k++) {
                float4 v = bb1[h * 4 + k];
                t1r[2 * k] += rh * v.x; t1i[2 * k] += rh * v.y;
                t1r[2 * k + 1] += rh * v.z; t1i[2 * k + 1] += rh * v.w;
            }
        }
#pragma unroll
        for (int p = 0; p < PP; p++) {
            float4 hv = h12v[p];
            float nr = hv.x * s1r[p] - hv.y * s1i[p] + t1r[p];
            float ni = hv.x * s1i[p] + hv.y * s1r[p] + t1i[p];
            s1r[p] = nr; s1i[p] = ni;
        }
    }
    scan_carry256(s1r, s1i, aL1, lane, w, aggA, aggS);
#pragma unroll 1
    for (int j = 0; j < len; j++) {
        int l = l0 + j;
        float xx = xl[l];
        size_t base = r0base(b, j, tid);
        float4 ra = r0q[base], rb = r0q[base + 256], rc = r0q[base + 512];
        float r0v[H] = {ra.x, ra.y, ra.z, ra.w, rb.x, rb.y, rb.z, rb.w, rc.x, rc.y, rc.z, rc.w};
        float t1r[PP], t1i[PP];
#pragma unroll
        for (int p = 0; p < PP; p++) {
            float4 g = g1v[p];
            t1r[p] = xx * g.x + g.z; t1i[p] = xx * g.y + g.w;
        }
#pragma unroll
        for (int h = 0; h < H; h++) {
            float rh = r0v[h];
#pragma unroll
            for (int k = 0; k < 4; k++) {
                float4 v = bb1[h * 4 + k];
                t1r[2 * k] += rh * v.x; t1i[2 * k] += rh * v.y;
                t1r[2 * k + 1] += rh * v.z; t1i[2 * k + 1] += rh * v.w;
            }
        }
#pragma unroll
        for (int p = 0; p < PP; p++) {
            float4 hv = h12v[p];
            float nr = hv.x * s1r[p] - hv.y * s1i[p] + t1r[p];
            float ni = hv.x * s1i[p] + hv.y * s1r[p] + t1i[p];
            s1r[p] = nr; s1i[p] = ni;
        }
        float rsv[H];
#pragma unroll
        for (int h = 0; h < H; h++) {
            float acc = 0.f;
#pragma unroll
            for (int k = 0; k < 4; k++) {
                float4 v = c1v[h * 4 + k];
                acc += s1r[2 * k] * v.x - s1i[2 * k] * v.y + s1r[2 * k + 1] * v.z - s1i[2 * k + 1] * v.w;
            }
            float4 f = f1v[h];
            float y1 = 2.f * acc + r0v[h] * f.y + xx * f0v[h].w + f.x;
            rsv[h] = r0v[h] + fmaxf(y1, 0.f);
        }
        r0q[base]       = make_float4(rsv[0], rsv[1], rsv[2], rsv[3]);
        r0q[base + 256] = make_float4(rsv[4], rsv[5], rsv[6], rsv[7]);
        r0q[base + 512] = make_float4(rsv[8], rsv[9], rsv[10], rsv[11]);
    }
}

// ---------------- layer 2: reads rs (coalesced), partial out + linear carry fixup ----------------
__global__ __launch_bounds__(256)
void k_l2(const float* __restrict__ x,
          const float* __restrict__ gprm,
          const float* __restrict__ rsbuf,
          float* __restrict__ out) {
    __shared__ float xl[SEQ];
    __shared__ float po[SEQ];
    __shared__ float2 aggA[4][PP], aggS[4][PP];
    const int tid = threadIdx.x, b = blockIdx.x;
    for (int i = tid; i < SEQ; i += 256) xl[i] = x[(size_t)b * SEQ + i];
    __syncthreads();
    const float4* g2v  = (const float4*)(gprm + O_G2);
    const float4* h12v = (const float4*)(gprm + O_H12);
    const float4* bb2  = (const float4*)(gprm + O_BB2);
    const float4* f1v  = (const float4*)(gprm + O_F1);
    const float2* cwv  = (const float2*)(gprm + O_CW);
    const float Sc0 = gprm[O_SC], Sc1 = gprm[O_SC + 1];
    const int w = tid >> 6, lane = tid & 63;
    const int len = (w == 3) ? 7 : 6;
    const int l0 = (w < 3) ? (w * 384 + lane * 6) : (1152 + lane * 7);
    const float2* aL2 = (const float2*)(gprm + ((w == 3) ? O_A7 : O_A6)) + 2 * PP;
    const float4* r0q = (const float4*)rsbuf;

    float s2r[PP], s2i[PP];
#pragma unroll
    for (int p = 0; p < PP; p++) { s2r[p] = 0.f; s2i[p] = 0.f; }
#pragma unroll 1
    for (int j = 0; j < len; j++) {
        int l = l0 + j;
        float xx = xl[l];
        size_t base = r0base(b, j, tid);
        float4 ra = r0q[base], rb = r0q[base + 256], rc = r0q[base + 512];
        float rsv[H] = {ra.x, ra.y, ra.z, ra.w, rb.x, rb.y, rb.z, rb.w, rc.x, rc.y, rc.z, rc.w};
        float t2r[PP], t2i[PP];
#pragma unroll
        for (int p = 0; p < PP; p++) {
            float4 g = g2v[p];
            t2r[p] = xx * g.x + g.z; t2i[p] = xx * g.y + g.w;
        }
        float o = Sc0 + xx * Sc1;
#pragma unroll
        for (int h = 0; h < H; h++) {
            float rs = rsv[h];
            o += rs * f1v[h].z;
#pragma unroll
            for (int k = 0; k < 4; k++) {
                float4 v = bb2[h * 4 + k];
                t2r[2 * k] += rs * v.x; t2i[2 * k] += rs * v.y;
                t2r[2 * k + 1] += rs * v.z; t2i[2 * k + 1] += rs * v.w;
            }
        }
#pragma unroll
        for (int p = 0; p < PP; p++) {
            float4 hv = h12v[p];
            float nr = hv.z * s2r[p] - hv.w * s2i[p] + t2r[p];
            float ni = hv.z * s2i[p] + hv.w * s2r[p] + t2i[p];
            s2r[p] = nr; s2i[p] = ni;
        }
        float acc2 = 0.f;
#pragma unroll
        for (int p = 0; p < PP; p++) {
            float2 c = cwv[p];
            acc2 += s2r[p] * c.x - s2i[p] * c.y;
        }
        po[l] = o + 2.f * acc2;   // partial (zero layer-2 carry)
    }
    scan_carry256(s2r, s2i, aL2, lane, w, aggA, aggS);  // -> carry2

    // fixup: += 2*Re(lam2^{j+1} * carry2 . cw)
    float tr[PP], ti_[PP], mr[PP], mi_[PP];
#pragma unroll
    for (int p = 0; p < PP; p++) {
        float2 c = cwv[p];
        tr[p]  = c.x * s2r[p] - c.y * s2i[p];
        ti_[p] = c.x * s2i[p] + c.y * s2r[p];
        float4 hv = h12v[p];
        mr[p] = hv.z; mi_[p] = hv.w;
    }
#pragma unroll 1
    for (int j = 0; j < len; j++) {
        float corr = 0.f;
#pragma unroll
        for (int p = 0; p < PP; p++) corr += mr[p] * tr[p] - mi_[p] * ti_[p];
        po[l0 + j] += 2.f * corr;
#pragma unroll
        for (int p = 0; p < PP; p++) {
            float4 hv = h12v[p];
            float t = mr[p] * hv.z - mi_[p] * hv.w;
            mi_[p] = mr[p] * hv.w + mi_[p] * hv.z;
            mr[p] = t;
        }
    }
    __syncthreads();
    float* orow = out + (size_t)b * SEQ;
    for (int i = tid; i < SEQ; i += 256) orow[i] = po[i];
}

extern "C" void kernel_launch(void* const* d_in, const int* in_sizes, int n_in,
                              void* d_out, int out_size, void* d_ws, size_t ws_size,
                              hipStream_t stream) {
    const float* x     = (const float*)d_in[0];
    const float* l1w   = (const float*)d_in[1];
    const float* l1b   = (const float*)d_in[2];
    const float* l2w   = (const float*)d_in[3];
    const float* l2b   = (const float*)d_in[4];
    const float* gam   = (const float*)d_in[5];
    const float* bet   = (const float*)d_in[6];
    const float* lamr  = (const float*)d_in[7];
    const float* lami  = (const float*)d_in[8];
    const float* bre   = (const float*)d_in[9];
    const float* bim   = (const float*)d_in[10];
    const float* cre   = (const float*)d_in[11];
    const float* cim   = (const float*)d_in[12];
    const float* dv    = (const float*)d_in[13];
    const float* lstep = (const float*)d_in[14];
    float* out = (float*)d_out;

    float* wsf     = (float*)d_ws;
    float* w_scale = wsf;                  // 1600
    float* w_shift = wsf + SEQ;            // 1600
    float* pS      = wsf + 2 * SEQ;        // 16*1600
    float* pQ      = pS + 16 * SEQ;        // 16*1600
    float* gprm    = pQ + 16 * SEQ;        // PRMF (padded to 1280)
    float* r0buf   = gprm + 1280;          // 1024*7*3*256 float4 = 88 MB (r0 then rs in place)

    k_prep<<<dim3(1), 64, 0, stream>>>(l1w, l1b, l2w, l2b, lamr, lami,
                                       bre, bim, cre, cim, dv, lstep, gprm);
    k_stats1<<<dim3(7, 16), 256, 0, stream>>>(x, pS, pQ);
    k_stats2<<<dim3(7), 256, 0, stream>>>(pS, pQ, l1w, l1b, gam, bet, w_scale, w_shift);
    k_l0<<<dim3(NB), 256, 0, stream>>>(x, gprm, w_scale, w_shift, r0buf);
    k_l1<<<dim3(NB), 256, 0, stream>>>(x, gprm, r0buf);
    k_l2<<<dim3(NB), 256, 0, stream>>>(x, gprm, r0buf, out);
}

// Round 11
// 383.355 us; speedup vs baseline: 1.9640x; 1.0478x over previous
//
#include <hip/hip_runtime.h>
#include <cmath>

#define SEQ 1600
#define NB  1024
#define H   12
#define PP  8

// ---- param block offsets (floats) in workspace ----
#define O_G0   0      // 8 x float4
#define O_H0   32
#define O_G1   64
#define O_G2   96
#define O_H12  128
#define O_C0V  160    // 48 x float4
#define O_C1V  352
#define O_BB1  544
#define O_BB2  736
#define O_F0   928    // 12 x float4
#define O_F1   976
#define O_CW   1024   // 8 x float2
#define O_A6   1040   // 24 x float2
#define O_A7   1088
#define O_SC   1136   // 2 floats
#define PRMF   1138

// r0 buffer: [b][j][q][tid] float4 planes, j<7, q<3, tid<256  (fully coalesced)
__device__ __forceinline__ size_t r0base(int b, int j, int tid) {
    return (((size_t)b * 7 + j) * 3) * 256 + tid;
}

// ---------------- BN stats ----------------
__global__ __launch_bounds__(256) void k_stats1(const float* __restrict__ x,
                                                float* __restrict__ pS,
                                                float* __restrict__ pQ) {
    int l = blockIdx.x * 256 + threadIdx.x;
    if (l >= SEQ) return;
    int b0 = blockIdx.y * 64;
    float s = 0.f, q = 0.f;
    for (int b = 0; b < 64; ++b) {
        float v = x[(size_t)(b0 + b) * SEQ + l];
        s += v; q += v * v;
    }
    pS[blockIdx.y * SEQ + l] = s;
    pQ[blockIdx.y * SEQ + l] = q;
}

__global__ __launch_bounds__(256) void k_stats2(const float* __restrict__ pS,
                                                const float* __restrict__ pQ,
                                                const float* __restrict__ w1,
                                                const float* __restrict__ b1,
                                                const float* __restrict__ gam,
                                                const float* __restrict__ bet,
                                                float* __restrict__ scale,
                                                float* __restrict__ shift) {
    int l = blockIdx.x * 256 + threadIdx.x;
    if (l >= SEQ) return;
    float wm = 0, wq = 0, wb = 0, bm = 0, bq = 0;
    for (int h = 0; h < H; h++) {
        float w = w1[h], b = b1[h];
        wm += w; wq += w * w; wb += w * b; bm += b; bq += b * b;
    }
    const float inv = 1.f / 12.f;
    wm *= inv; wq *= inv; wb *= inv; bm *= inv; bq *= inv;
    float s = 0, q = 0;
    for (int k = 0; k < 16; k++) { s += pS[k * SEQ + l]; q += pQ[k * SEQ + l]; }
    float ex = s * (1.f / NB), exx = q * (1.f / NB);
    float mean = ex * wm + bm;
    float e2   = exx * wq + 2.f * ex * wb + bq;
    float var  = e2 - mean * mean;
    float sc   = gam[l] * rsqrtf(var + 1e-5f);
    scale[l] = sc;
    shift[l] = bet[l] - mean * sc;
}

// ---------------- one-time derived parameters ----------------
__global__ void k_prep(const float* __restrict__ l1w, const float* __restrict__ l1b,
                       const float* __restrict__ l2w, const float* __restrict__ l2b,
                       const float* __restrict__ lamr, const float* __restrict__ lami,
                       const float* __restrict__ bre, const float* __restrict__ bim,
                       const float* __restrict__ cre, const float* __restrict__ cim,
                       const float* __restrict__ dv,  const float* __restrict__ lstep,
                       float* __restrict__ gprm) {
    const int t = threadIdx.x;
    if (t < 48) {   // C matrices layers 0,1 as float4 (re,im,re,im)
        int h = t >> 2, k = t & 3, p0 = 2 * k, p1 = 2 * k + 1;
        gprm[O_C0V + 4 * t + 0] = cre[h * PP + p0];
        gprm[O_C0V + 4 * t + 1] = cim[h * PP + p0];
        gprm[O_C0V + 4 * t + 2] = cre[h * PP + p1];
        gprm[O_C0V + 4 * t + 3] = cim[h * PP + p1];
        gprm[O_C1V + 4 * t + 0] = cre[96 + h * PP + p0];
        gprm[O_C1V + 4 * t + 1] = cim[96 + h * PP + p0];
        gprm[O_C1V + 4 * t + 2] = cre[96 + h * PP + p1];
        gprm[O_C1V + 4 * t + 3] = cim[96 + h * PP + p1];
    }
    if (t < H) {
        float w = l1w[t], bb = l1b[t];
        float d0 = dv[t], d1 = dv[H + t], d2 = dv[2 * H + t];
        gprm[O_F0 + 4 * t + 0] = w * d0;
        gprm[O_F0 + 4 * t + 1] = bb * d0;
        gprm[O_F0 + 4 * t + 2] = d0;
        gprm[O_F0 + 4 * t + 3] = w * d1;
        gprm[O_F1 + 4 * t + 0] = bb * d1;
        gprm[O_F1 + 4 * t + 1] = d1;
        gprm[O_F1 + 4 * t + 2] = l2w[t] * d2;
        gprm[O_F1 + 4 * t + 3] = 0.f;
    }
    if (t == 0) {
        float s0 = l2b[0], s1 = 0.f;
        for (int h = 0; h < H; h++) {
            float dw = l2w[h] * dv[2 * H + h];
            s0 += l1b[h] * dw; s1 += l1w[h] * dw;
        }
        gprm[O_SC + 0] = s0; gprm[O_SC + 1] = s1;
    }
    if (t < 24) {
        int L = t >> 3, p = t & 7;
        float stp = expf(lstep[L * PP + p]);
        float lr = lamr[L * PP + p], li = lami[L * PP + p];
        float er = expf(lr * stp);
        float lbr = er * cosf(li * stp), lbi = er * sinf(li * stp);   // lam_bar
        float p2r = lbr * lbr - lbi * lbi, p2i = 2.f * lbr * lbi;
        float p4r = p2r * p2r - p2i * p2i, p4i = 2.f * p2r * p2i;
        float p6r = p4r * p2r - p4i * p2i, p6i = p4r * p2i + p4i * p2r;
        float p7r = p6r * lbr - p6i * lbi, p7i = p6r * lbi + p6i * lbr;
        gprm[O_A6 + 2 * (L * PP + p) + 0] = p6r;
        gprm[O_A6 + 2 * (L * PP + p) + 1] = p6i;
        gprm[O_A7 + 2 * (L * PP + p) + 0] = p7r;
        gprm[O_A7 + 2 * (L * PP + p) + 1] = p7i;
        float den = lr * lr + li * li;
        float fr = ((lbr - 1.f) * lr + lbi * li) / den;
        float fi = (lbi * lr - (lbr - 1.f) * li) / den;
        float sAr = 0, sAi = 0, sBr = 0, sBi = 0, sCr = 0, sCi = 0;
        for (int h = 0; h < H; h++) {
            float brr = bre[L * 96 + p * H + h], bii = bim[L * 96 + p * H + h];
            float vr = fr * brr - fi * bii, vi = fr * bii + fi * brr;  // b_bar[p,h]
            float w = l1w[h], bb = l1b[h];
            sAr += w * vr; sAi += w * vi; sBr += bb * vr; sBi += bb * vi; sCr += vr; sCi += vi;
            int fidx = h * 16 + (p >> 1) * 4 + (p & 1) * 2;
            if (L == 1)      { gprm[O_BB1 + fidx] = vr; gprm[O_BB1 + fidx + 1] = vi; }
            else if (L == 2) { gprm[O_BB2 + fidx] = vr; gprm[O_BB2 + fidx + 1] = vi; }
        }
        if (L == 0) {
            gprm[O_G0 + 4 * p + 0] = sAr; gprm[O_G0 + 4 * p + 1] = sAi;
            gprm[O_G0 + 4 * p + 2] = sBr; gprm[O_G0 + 4 * p + 3] = sBi;
            gprm[O_H0 + 4 * p + 0] = sCr; gprm[O_H0 + 4 * p + 1] = sCi;
            gprm[O_H0 + 4 * p + 2] = lbr; gprm[O_H0 + 4 * p + 3] = lbi;
        } else if (L == 1) {
            gprm[O_G1 + 4 * p + 0] = sAr; gprm[O_G1 + 4 * p + 1] = sAi;
            gprm[O_G1 + 4 * p + 2] = sBr; gprm[O_G1 + 4 * p + 3] = sBi;
            gprm[O_H12 + 4 * p + 0] = lbr; gprm[O_H12 + 4 * p + 1] = lbi;
        } else {
            gprm[O_G2 + 4 * p + 0] = sAr; gprm[O_G2 + 4 * p + 1] = sAi;
            gprm[O_G2 + 4 * p + 2] = sBr; gprm[O_G2 + 4 * p + 3] = sBi;
            gprm[O_H12 + 4 * p + 2] = lbr; gprm[O_H12 + 4 * p + 3] = lbi;
            float swr = 0, swi = 0;
            for (int hh = 0; hh < H; hh++) {
                float wv = l2w[hh];
                swr += wv * cre[192 + hh * PP + p];
                swi += wv * cim[192 + hh * PP + p];
            }
            gprm[O_CW + 2 * p + 0] = swr; gprm[O_CW + 2 * p + 1] = swi;
        }
    }
}

// ---- hierarchical carry scan across 256 threads (4 waves x 64 lanes) ----
__device__ __forceinline__ void scan_carry256(float* Sr, float* Si,
                                              const float2* a_init,
                                              int lane, int w,
                                              float2 (*aggA)[PP], float2 (*aggS)[PP]) {
    float Ar[PP], Ai[PP];
#pragma unroll
    for (int p = 0; p < PP; p++) { float2 a = a_init[p]; Ar[p] = a.x; Ai[p] = a.y; }
#pragma unroll
    for (int d = 1; d < 64; d <<= 1) {
#pragma unroll
        for (int p = 0; p < PP; p++) {
            float fSr = __shfl_up(Sr[p], (unsigned)d, 64);
            float fSi = __shfl_up(Si[p], (unsigned)d, 64);
            float fAr = __shfl_up(Ar[p], (unsigned)d, 64);
            float fAi = __shfl_up(Ai[p], (unsigned)d, 64);
            if (lane >= d) {
                float nsr = Ar[p] * fSr - Ai[p] * fSi + Sr[p];
                float nsi = Ar[p] * fSi + Ai[p] * fSr + Si[p];
                float nar = fAr * Ar[p] - fAi * Ai[p];
                float nai = fAr * Ai[p] + fAi * Ar[p];
                Sr[p] = nsr; Si[p] = nsi; Ar[p] = nar; Ai[p] = nai;
            }
        }
    }
    __syncthreads();   // protect agg buffer from previous use
    if (lane == 63) {
#pragma unroll
        for (int p = 0; p < PP; p++) {
            aggA[w][p] = make_float2(Ar[p], Ai[p]);
            aggS[w][p] = make_float2(Sr[p], Si[p]);
        }
    }
    __syncthreads();
    float eSr[PP], eSi[PP], eAr[PP], eAi[PP];
#pragma unroll
    for (int p = 0; p < PP; p++) {
        float sr = __shfl_up(Sr[p], 1u, 64);
        float si = __shfl_up(Si[p], 1u, 64);
        float ar = __shfl_up(Ar[p], 1u, 64);
        float ai = __shfl_up(Ai[p], 1u, 64);
        eSr[p] = (lane > 0) ? sr : 0.f;
        eSi[p] = (lane > 0) ? si : 0.f;
        eAr[p] = (lane > 0) ? ar : 1.f;
        eAi[p] = (lane > 0) ? ai : 0.f;
    }
    float Pr[PP], Pi[PP];
#pragma unroll
    for (int p = 0; p < PP; p++) { Pr[p] = 0.f; Pi[p] = 0.f; }
    for (int w2 = 0; w2 < w; w2++) {
#pragma unroll
        for (int p = 0; p < PP; p++) {
            float2 a = aggA[w2][p];
            float2 s = aggS[w2][p];
            float nr = a.x * Pr[p] - a.y * Pi[p] + s.x;
            float ni = a.x * Pi[p] + a.y * Pr[p] + s.y;
            Pr[p] = nr; Pi[p] = ni;
        }
    }
#pragma unroll
    for (int p = 0; p < PP; p++) {
        Sr[p] = eAr[p] * Pr[p] - eAi[p] * Pi[p] + eSr[p];
        Si[p] = eAr[p] * Pi[p] + eAi[p] * Pr[p] + eSi[p];
    }
}

// ---------------- layer 0: BN-folded scan, writes r0 (coalesced layout) ----------------
__global__ __launch_bounds__(256)
void k_l0(const float* __restrict__ x,
          const float* __restrict__ gprm,
          const float* __restrict__ g_scale, const float* __restrict__ g_shift,
          float* __restrict__ r0buf) {
    __shared__ float xl[SEQ], scl[SEQ], shl[SEQ];
    __shared__ float2 aggA[4][PP], aggS[4][PP];
    const int tid = threadIdx.x, b = blockIdx.x;
    for (int i = tid; i < SEQ; i += 256) {
        xl[i] = x[(size_t)b * SEQ + i];
        scl[i] = g_scale[i];
        shl[i] = g_shift[i];
    }
    __syncthreads();
    const float4* g0v = (const float4*)(gprm + O_G0);
    const float4* h0v = (const float4*)(gprm + O_H0);
    const float4* c0v = (const float4*)(gprm + O_C0V);
    const float4* f0v = (const float4*)(gprm + O_F0);
    const int w = tid >> 6, lane = tid & 63;
    const int len = (w == 3) ? 7 : 6;
    const int l0 = (w < 3) ? (w * 384 + lane * 6) : (1152 + lane * 7);
    const float2* aL0 = (const float2*)(gprm + ((w == 3) ? O_A7 : O_A6));

    float s0r[PP], s0i[PP];
#pragma unroll
    for (int p = 0; p < PP; p++) { s0r[p] = 0.f; s0i[p] = 0.f; }
#pragma unroll 1
    for (int j = 0; j < len; j++) {
        int l = l0 + j;
        float xx = xl[l], sc = scl[l], sh = shl[l];
        float xs = xx * sc;
#pragma unroll
        for (int p = 0; p < PP; p++) {
            float4 g = g0v[p]; float4 hv = h0v[p];
            float bur = xs * g.x + sc * g.z + sh * hv.x;
            float bui = xs * g.y + sc * g.w + sh * hv.y;
            float nr = hv.z * s0r[p] - hv.w * s0i[p] + bur;
            float ni = hv.z * s0i[p] + hv.w * s0r[p] + bui;
            s0r[p] = nr; s0i[p] = ni;
        }
    }
    scan_carry256(s0r, s0i, aL0, lane, w, aggA, aggS);
    float4* r0q = (float4*)r0buf;
#pragma unroll 1
    for (int j = 0; j < len; j++) {
        int l = l0 + j;
        float xx = xl[l], sc = scl[l], sh = shl[l];
        float xs = xx * sc;
#pragma unroll
        for (int p = 0; p < PP; p++) {
            float4 g = g0v[p]; float4 hv = h0v[p];
            float bur = xs * g.x + sc * g.z + sh * hv.x;
            float bui = xs * g.y + sc * g.w + sh * hv.y;
            float nr = hv.z * s0r[p] - hv.w * s0i[p] + bur;
            float ni = hv.z * s0i[p] + hv.w * s0r[p] + bui;
            s0r[p] = nr; s0i[p] = ni;
        }
        float r0v[H];
#pragma unroll
        for (int h = 0; h < H; h++) {
            float acc = 0.f;
#pragma unroll
            for (int k = 0; k < 4; k++) {
                float4 v = c0v[h * 4 + k];
                acc += s0r[2 * k] * v.x - s0i[2 * k] * v.y + s0r[2 * k + 1] * v.z - s0i[2 * k + 1] * v.w;
            }
            float4 f = f0v[h];
            float y0 = 2.f * acc + xs * f.x + sc * f.y + sh * f.z;
            r0v[h] = fmaxf(y0, 0.f);
        }
        size_t base = r0base(b, j, tid);
        r0q[base]       = make_float4(r0v[0], r0v[1], r0v[2], r0v[3]);
        r0q[base + 256] = make_float4(r0v[4], r0v[5], r0v[6], r0v[7]);
        r0q[base + 512] = make_float4(r0v[8], r0v[9], r0v[10], r0v[11]);
    }
}

// ---------------- layers 1+2 fused (scalar params): 2 passes over r0, rs in regs ----------------
__global__ __launch_bounds__(256)
void k_l12(const float* __restrict__ x,
           const float* __restrict__ gprm,
           const float* __restrict__ r0buf,
           float* __restrict__ out) {
    __shared__ float xl[SEQ];
    __shared__ float po[SEQ];
    __shared__ float2 aggA[4][PP], aggS[4][PP];
    const int tid = threadIdx.x, b = blockIdx.x;
    for (int i = tid; i < SEQ; i += 256) xl[i] = x[(size_t)b * SEQ + i];
    __syncthreads();
    const float4* g1v  = (const float4*)(gprm + O_G1);
    const float4* g2v  = (const float4*)(gprm + O_G2);
    const float4* h12v = (const float4*)(gprm + O_H12);
    const float4* c1v  = (const float4*)(gprm + O_C1V);
    const float4* bb1  = (const float4*)(gprm + O_BB1);
    const float4* bb2  = (const float4*)(gprm + O_BB2);
    const float4* f0v  = (const float4*)(gprm + O_F0);
    const float4* f1v  = (const float4*)(gprm + O_F1);
    const float2* cwv  = (const float2*)(gprm + O_CW);
    const float Sc0 = gprm[O_SC], Sc1 = gprm[O_SC + 1];
    const int w = tid >> 6, lane = tid & 63;
    const int len = (w == 3) ? 7 : 6;
    const int l0 = (w < 3) ? (w * 384 + lane * 6) : (1152 + lane * 7);
    const float2* aL1 = (const float2*)(gprm + ((w == 3) ? O_A7 : O_A6)) + 1 * PP;
    const float2* aL2 = (const float2*)(gprm + ((w == 3) ? O_A7 : O_A6)) + 2 * PP;
    const float4* r0q = (const float4*)r0buf;

    float s1r[PP], s1i[PP];
#pragma unroll
    for (int p = 0; p < PP; p++) { s1r[p] = 0.f; s1i[p] = 0.f; }

    // ---- pass 1: layer-1 local scan ----
#pragma unroll 1
    for (int j = 0; j < len; j++) {
        int l = l0 + j;
        float xx = xl[l];
        size_t base = r0base(b, j, tid);
        float4 ra = r0q[base], rb = r0q[base + 256], rc = r0q[base + 512];
        float r0v[H] = {ra.x, ra.y, ra.z, ra.w, rb.x, rb.y, rb.z, rb.w, rc.x, rc.y, rc.z, rc.w};
        float t1r[PP], t1i[PP];
#pragma unroll
        for (int p = 0; p < PP; p++) {
            float4 g = g1v[p];
            t1r[p] = xx * g.x + g.z; t1i[p] = xx * g.y + g.w;
        }
#pragma unroll
        for (int h = 0; h < H; h++) {
            float rh = r0v[h];
#pragma unroll
            for (int k = 0; k < 4; k++) {
                float4 v = bb1[h * 4 + k];
                t1r[2 * k] += rh * v.x; t1i[2 * k] += rh * v.y;
                t1r[2 * k + 1] += rh * v.z; t1i[2 * k + 1] += rh * v.w;
            }
        }
#pragma unroll
        for (int p = 0; p < PP; p++) {
            float4 hv = h12v[p];
            float nr = hv.x * s1r[p] - hv.y * s1i[p] + t1r[p];
            float ni = hv.x * s1i[p] + hv.y * s1r[p] + t1i[p];
            s1r[p] = nr; s1i[p] = ni;
        }
    }
    scan_carry256(s1r, s1i, aL1, lane, w, aggA, aggS);

    // ---- pass 2: layer-1 exact + layer-2 local + partial out (rs in regs only) ----
    float s2r[PP], s2i[PP];
#pragma unroll
    for (int p = 0; p < PP; p++) { s2r[p] = 0.f; s2i[p] = 0.f; }
#pragma unroll 1
    for (int j = 0; j < len; j++) {
        int l = l0 + j;
        float xx = xl[l];
        size_t base = r0base(b, j, tid);
        float4 ra = r0q[base], rb = r0q[base + 256], rc = r0q[base + 512];
        float r0v[H] = {ra.x, ra.y, ra.z, ra.w, rb.x, rb.y, rb.z, rb.w, rc.x, rc.y, rc.z, rc.w};
        float t1r[PP], t1i[PP];
#pragma unroll
        for (int p = 0; p < PP; p++) {
            float4 g = g1v[p];
            t1r[p] = xx * g.x + g.z; t1i[p] = xx * g.y + g.w;
        }
#pragma unroll
        for (int h = 0; h < H; h++) {
            float rh = r0v[h];
#pragma unroll
            for (int k = 0; k < 4; k++) {
                float4 v = bb1[h * 4 + k];
                t1r[2 * k] += rh * v.x; t1i[2 * k] += rh * v.y;
                t1r[2 * k + 1] += rh * v.z; t1i[2 * k + 1] += rh * v.w;
            }
        }
#pragma unroll
        for (int p = 0; p < PP; p++) {
            float4 hv = h12v[p];
            float nr = hv.x * s1r[p] - hv.y * s1i[p] + t1r[p];
            float ni = hv.x * s1i[p] + hv.y * s1r[p] + t1i[p];
            s1r[p] = nr; s1i[p] = ni;
        }
        // layer-2 local recurrence consuming rs = r0 + relu(y1) straight from regs
        float t2r[PP], t2i[PP];
#pragma unroll
        for (int p = 0; p < PP; p++) {
            float4 g = g2v[p];
            t2r[p] = xx * g.x + g.z; t2i[p] = xx * g.y + g.w;
        }
        float o = Sc0 + xx * Sc1;
#pragma unroll
        for (int h = 0; h < H; h++) {
            float acc = 0.f;
#pragma unroll
            for (int k = 0; k < 4; k++) {
                float4 v = c1v[h * 4 + k];
                acc += s1r[2 * k] * v.x - s1i[2 * k] * v.y + s1r[2 * k + 1] * v.z - s1i[2 * k + 1] * v.w;
            }
            float4 f = f1v[h];
            float y1 = 2.f * acc + r0v[h] * f.y + xx * f0v[h].w + f.x;
            float rs = r0v[h] + fmaxf(y1, 0.f);
            o += rs * f.z;
#pragma unroll
            for (int k = 0; k < 4; k++) {
                float4 v = bb2[h * 4 + k];
                t2r[2 * k] += rs * v.x; t2i[2 * k] += rs * v.y;
                t2r[2 * k + 1] += rs * v.z; t2i[2 * k + 1] += rs * v.w;
            }
        }
#pragma unroll
        for (int p = 0; p < PP; p++) {
            float4 hv = h12v[p];
            float nr = hv.z * s2r[p] - hv.w * s2i[p] + t2r[p];
            float ni = hv.z * s2i[p] + hv.w * s2r[p] + t2i[p];
            s2r[p] = nr; s2i[p] = ni;
        }
        float acc2 = 0.f;
#pragma unroll
        for (int p = 0; p < PP; p++) {
            float2 c = cwv[p];
            acc2 += s2r[p] * c.x - s2i[p] * c.y;
        }
        po[l] = o + 2.f * acc2;   // partial (zero layer-2 carry)
    }
    scan_carry256(s2r, s2i, aL2, lane, w, aggA, aggS);  // -> carry2

    // fixup: += 2*Re(lam2^{j+1} * carry2 . cw)
    float tr[PP], ti_[PP], mr[PP], mi_[PP];
#pragma unroll
    for (int p = 0; p < PP; p++) {
        float2 c = cwv[p];
        tr[p]  = c.x * s2r[p] - c.y * s2i[p];
        ti_[p] = c.x * s2i[p] + c.y * s2r[p];
        float4 hv = h12v[p];
        mr[p] = hv.z; mi_[p] = hv.w;
    }
#pragma unroll 1
    for (int j = 0; j < len; j++) {
        float corr = 0.f;
#pragma unroll
        for (int p = 0; p < PP; p++) corr += mr[p] * tr[p] - mi_[p] * ti_[p];
        po[l0 + j] += 2.f * corr;
#pragma unroll
        for (int p = 0; p < PP; p++) {
            float4 hv = h12v[p];
            float t = mr[p] * hv.z - mi_[p] * hv.w;
            mi_[p] = mr[p] * hv.w + mi_[p] * hv.z;
            mr[p] = t;
        }
    }
    __syncthreads();
    float* orow = out + (size_t)b * SEQ;
    for (int i = tid; i < SEQ; i += 256) orow[i] = po[i];
}

extern "C" void kernel_launch(void* const* d_in, const int* in_sizes, int n_in,
                              void* d_out, int out_size, void* d_ws, size_t ws_size,
                              hipStream_t stream) {
    const float* x     = (const float*)d_in[0];
    const float* l1w   = (const float*)d_in[1];
    const float* l1b   = (const float*)d_in[2];
    const float* l2w   = (const float*)d_in[3];
    const float* l2b   = (const float*)d_in[4];
    const float* gam   = (const float*)d_in[5];
    const float* bet   = (const float*)d_in[6];
    const float* lamr  = (const float*)d_in[7];
    const float* lami  = (const float*)d_in[8];
    const float* bre   = (const float*)d_in[9];
    const float* bim   = (const float*)d_in[10];
    const float* cre   = (const float*)d_in[11];
    const float* cim   = (const float*)d_in[12];
    const float* dv    = (const float*)d_in[13];
    const float* lstep = (const float*)d_in[14];
    float* out = (float*)d_out;

    float* wsf     = (float*)d_ws;
    float* w_scale = wsf;                  // 1600
    float* w_shift = wsf + SEQ;            // 1600
    float* pS      = wsf + 2 * SEQ;        // 16*1600
    float* pQ      = pS + 16 * SEQ;        // 16*1600
    float* gprm    = pQ + 16 * SEQ;        // PRMF (padded to 1280)
    float* r0buf   = gprm + 1280;          // 1024*7*3*256 float4 = 88 MB

    k_prep<<<dim3(1), 64, 0, stream>>>(l1w, l1b, l2w, l2b, lamr, lami,
                                       bre, bim, cre, cim, dv, lstep, gprm);
    k_stats1<<<dim3(7, 16), 256, 0, stream>>>(x, pS, pQ);
    k_stats2<<<dim3(7), 256, 0, stream>>>(pS, pQ, l1w, l1b, gam, bet, w_scale, w_shift);
    k_l0<<<dim3(NB), 256, 0, stream>>>(x, gprm, w_scale, w_shift, r0buf);
    k_l12<<<dim3(NB), 256, 0, stream>>>(x, gprm, r0buf, out);
}

// Round 12
// 327.159 us; speedup vs baseline: 2.3013x; 1.1718x over previous
//
#include <hip/hip_runtime.h>
#include <cmath>

#define SEQ 1600
#define NB  1024
#define H   12
#define PP  8

// ---- param block offsets (floats) in workspace ----
#define O_G0   0      // 8 x float4
#define O_H0   32
#define O_G1   64
#define O_G2   96
#define O_H12  128
#define O_C0V  160    // 48 x float4
#define O_C1V  352
#define O_BB1  544
#define O_BB2  736
#define O_F0   928    // 12 x float4
#define O_F1   976
#define O_CW   1024   // 8 x float2
#define O_A6   1040   // 24 x float2
#define O_A7   1088
#define O_SC   1136   // 2 floats
#define PRMF   1138

// ---------------- BN stats ----------------
__global__ __launch_bounds__(256) void k_stats1(const float* __restrict__ x,
                                                float* __restrict__ pS,
                                                float* __restrict__ pQ) {
    int l = blockIdx.x * 256 + threadIdx.x;
    if (l >= SEQ) return;
    int b0 = blockIdx.y * 64;
    float s = 0.f, q = 0.f;
    for (int b = 0; b < 64; ++b) {
        float v = x[(size_t)(b0 + b) * SEQ + l];
        s += v; q += v * v;
    }
    pS[blockIdx.y * SEQ + l] = s;
    pQ[blockIdx.y * SEQ + l] = q;
}

__global__ __launch_bounds__(256) void k_stats2(const float* __restrict__ pS,
                                                const float* __restrict__ pQ,
                                                const float* __restrict__ w1,
                                                const float* __restrict__ b1,
                                                const float* __restrict__ gam,
                                                const float* __restrict__ bet,
                                                float* __restrict__ scale,
                                                float* __restrict__ shift) {
    int l = blockIdx.x * 256 + threadIdx.x;
    if (l >= SEQ) return;
    float wm = 0, wq = 0, wb = 0, bm = 0, bq = 0;
    for (int h = 0; h < H; h++) {
        float w = w1[h], b = b1[h];
        wm += w; wq += w * w; wb += w * b; bm += b; bq += b * b;
    }
    const float inv = 1.f / 12.f;
    wm *= inv; wq *= inv; wb *= inv; bm *= inv; bq *= inv;
    float s = 0, q = 0;
    for (int k = 0; k < 16; k++) { s += pS[k * SEQ + l]; q += pQ[k * SEQ + l]; }
    float ex = s * (1.f / NB), exx = q * (1.f / NB);
    float mean = ex * wm + bm;
    float e2   = exx * wq + 2.f * ex * wb + bq;
    float var  = e2 - mean * mean;
    float sc   = gam[l] * rsqrtf(var + 1e-5f);
    scale[l] = sc;
    shift[l] = bet[l] - mean * sc;
}

// ---------------- one-time derived parameters ----------------
__global__ void k_prep(const float* __restrict__ l1w, const float* __restrict__ l1b,
                       const float* __restrict__ l2w, const float* __restrict__ l2b,
                       const float* __restrict__ lamr, const float* __restrict__ lami,
                       const float* __restrict__ bre, const float* __restrict__ bim,
                       const float* __restrict__ cre, const float* __restrict__ cim,
                       const float* __restrict__ dv,  const float* __restrict__ lstep,
                       float* __restrict__ gprm) {
    const int t = threadIdx.x;
    if (t < 48) {   // C matrices layers 0,1 as float4 (re,im,re,im)
        int h = t >> 2, k = t & 3, p0 = 2 * k, p1 = 2 * k + 1;
        gprm[O_C0V + 4 * t + 0] = cre[h * PP + p0];
        gprm[O_C0V + 4 * t + 1] = cim[h * PP + p0];
        gprm[O_C0V + 4 * t + 2] = cre[h * PP + p1];
        gprm[O_C0V + 4 * t + 3] = cim[h * PP + p1];
        gprm[O_C1V + 4 * t + 0] = cre[96 + h * PP + p0];
        gprm[O_C1V + 4 * t + 1] = cim[96 + h * PP + p0];
        gprm[O_C1V + 4 * t + 2] = cre[96 + h * PP + p1];
        gprm[O_C1V + 4 * t + 3] = cim[96 + h * PP + p1];
    }
    if (t < H) {
        float w = l1w[t], bb = l1b[t];
        float d0 = dv[t], d1 = dv[H + t], d2 = dv[2 * H + t];
        gprm[O_F0 + 4 * t + 0] = w * d0;
        gprm[O_F0 + 4 * t + 1] = bb * d0;
        gprm[O_F0 + 4 * t + 2] = d0;
        gprm[O_F0 + 4 * t + 3] = w * d1;
        gprm[O_F1 + 4 * t + 0] = bb * d1;
        gprm[O_F1 + 4 * t + 1] = d1;
        gprm[O_F1 + 4 * t + 2] = l2w[t] * d2;
        gprm[O_F1 + 4 * t + 3] = 0.f;
    }
    if (t == 0) {
        float s0 = l2b[0], s1 = 0.f;
        for (int h = 0; h < H; h++) {
            float dw = l2w[h] * dv[2 * H + h];
            s0 += l1b[h] * dw; s1 += l1w[h] * dw;
        }
        gprm[O_SC + 0] = s0; gprm[O_SC + 1] = s1;
    }
    if (t < 24) {
        int L = t >> 3, p = t & 7;
        float stp = expf(lstep[L * PP + p]);
        float lr = lamr[L * PP + p], li = lami[L * PP + p];
        float er = expf(lr * stp);
        float lbr = er * cosf(li * stp), lbi = er * sinf(li * stp);   // lam_bar
        float p2r = lbr * lbr - lbi * lbi, p2i = 2.f * lbr * lbi;
        float p4r = p2r * p2r - p2i * p2i, p4i = 2.f * p2r * p2i;
        float p6r = p4r * p2r - p4i * p2i, p6i = p4r * p2i + p4i * p2r;
        float p7r = p6r * lbr - p6i * lbi, p7i = p6r * lbi + p6i * lbr;
        gprm[O_A6 + 2 * (L * PP + p) + 0] = p6r;
        gprm[O_A6 + 2 * (L * PP + p) + 1] = p6i;
        gprm[O_A7 + 2 * (L * PP + p) + 0] = p7r;
        gprm[O_A7 + 2 * (L * PP + p) + 1] = p7i;
        float den = lr * lr + li * li;
        float fr = ((lbr - 1.f) * lr + lbi * li) / den;
        float fi = (lbi * lr - (lbr - 1.f) * li) / den;
        float sAr = 0, sAi = 0, sBr = 0, sBi = 0, sCr = 0, sCi = 0;
        for (int h = 0; h < H; h++) {
            float brr = bre[L * 96 + p * H + h], bii = bim[L * 96 + p * H + h];
            float vr = fr * brr - fi * bii, vi = fr * bii + fi * brr;  // b_bar[p,h]
            float w = l1w[h], bb = l1b[h];
            sAr += w * vr; sAi += w * vi; sBr += bb * vr; sBi += bb * vi; sCr += vr; sCi += vi;
            int fidx = h * 16 + (p >> 1) * 4 + (p & 1) * 2;
            if (L == 1)      { gprm[O_BB1 + fidx] = vr; gprm[O_BB1 + fidx + 1] = vi; }
            else if (L == 2) { gprm[O_BB2 + fidx] = vr; gprm[O_BB2 + fidx + 1] = vi; }
        }
        if (L == 0) {
            gprm[O_G0 + 4 * p + 0] = sAr; gprm[O_G0 + 4 * p + 1] = sAi;
            gprm[O_G0 + 4 * p + 2] = sBr; gprm[O_G0 + 4 * p + 3] = sBi;
            gprm[O_H0 + 4 * p + 0] = sCr; gprm[O_H0 + 4 * p + 1] = sCi;
            gprm[O_H0 + 4 * p + 2] = lbr; gprm[O_H0 + 4 * p + 3] = lbi;
        } else if (L == 1) {
            gprm[O_G1 + 4 * p + 0] = sAr; gprm[O_G1 + 4 * p + 1] = sAi;
            gprm[O_G1 + 4 * p + 2] = sBr; gprm[O_G1 + 4 * p + 3] = sBi;
            gprm[O_H12 + 4 * p + 0] = lbr; gprm[O_H12 + 4 * p + 1] = lbi;
        } else {
            gprm[O_G2 + 4 * p + 0] = sAr; gprm[O_G2 + 4 * p + 1] = sAi;
            gprm[O_G2 + 4 * p + 2] = sBr; gprm[O_G2 + 4 * p + 3] = sBi;
            gprm[O_H12 + 4 * p + 2] = lbr; gprm[O_H12 + 4 * p + 3] = lbi;
            float swr = 0, swi = 0;
            for (int hh = 0; hh < H; hh++) {
                float wv = l2w[hh];
                swr += wv * cre[192 + hh * PP + p];
                swi += wv * cim[192 + hh * PP + p];
            }
            gprm[O_CW + 2 * p + 0] = swr; gprm[O_CW + 2 * p + 1] = swi;
        }
    }
}

// ---- hierarchical carry scan across 256 threads (4 waves x 64 lanes) ----
__device__ __forceinline__ void scan_carry256(float* Sr, float* Si,
                                              const float2* a_init,
                                              int lane, int w,
                                              float2 (*aggA)[PP], float2 (*aggS)[PP]) {
    float Ar[PP], Ai[PP];
#pragma unroll
    for (int p = 0; p < PP; p++) { float2 a = a_init[p]; Ar[p] = a.x; Ai[p] = a.y; }
#pragma unroll
    for (int d = 1; d < 64; d <<= 1) {
#pragma unroll
        for (int p = 0; p < PP; p++) {
            float fSr = __shfl_up(Sr[p], (unsigned)d, 64);
            float fSi = __shfl_up(Si[p], (unsigned)d, 64);
            float fAr = __shfl_up(Ar[p], (unsigned)d, 64);
            float fAi = __shfl_up(Ai[p], (unsigned)d, 64);
            if (lane >= d) {
                float nsr = Ar[p] * fSr - Ai[p] * fSi + Sr[p];
                float nsi = Ar[p] * fSi + Ai[p] * fSr + Si[p];
                float nar = fAr * Ar[p] - fAi * Ai[p];
                float nai = fAr * Ai[p] + fAi * Ar[p];
                Sr[p] = nsr; Si[p] = nsi; Ar[p] = nar; Ai[p] = nai;
            }
        }
    }
    __syncthreads();   // protect agg buffer from previous use
    if (lane == 63) {
#pragma unroll
        for (int p = 0; p < PP; p++) {
            aggA[w][p] = make_float2(Ar[p], Ai[p]);
            aggS[w][p] = make_float2(Sr[p], Si[p]);
        }
    }
    __syncthreads();
    float eSr[PP], eSi[PP], eAr[PP], eAi[PP];
#pragma unroll
    for (int p = 0; p < PP; p++) {
        float sr = __shfl_up(Sr[p], 1u, 64);
        float si = __shfl_up(Si[p], 1u, 64);
        float ar = __shfl_up(Ar[p], 1u, 64);
        float ai = __shfl_up(Ai[p], 1u, 64);
        eSr[p] = (lane > 0) ? sr : 0.f;
        eSi[p] = (lane > 0) ? si : 0.f;
        eAr[p] = (lane > 0) ? ar : 1.f;
        eAi[p] = (lane > 0) ? ai : 0.f;
    }
    float Pr[PP], Pi[PP];
#pragma unroll
    for (int p = 0; p < PP; p++) { Pr[p] = 0.f; Pi[p] = 0.f; }
    for (int w2 = 0; w2 < w; w2++) {
#pragma unroll
        for (int p = 0; p < PP; p++) {
            float2 a = aggA[w2][p];
            float2 s = aggS[w2][p];
            float nr = a.x * Pr[p] - a.y * Pi[p] + s.x;
            float ni = a.x * Pi[p] + a.y * Pr[p] + s.y;
            Pr[p] = nr; Pi[p] = ni;
        }
    }
#pragma unroll
    for (int p = 0; p < PP; p++) {
        Sr[p] = eAr[p] * Pr[p] - eAi[p] * Pi[p] + eSr[p];
        Si[p] = eAr[p] * Pi[p] + eAi[p] * Pr[p] + eSi[p];
    }
}

// ---------------- fully fused: 3 layers, 1 block per batch, scalar params ----------------
__global__ __launch_bounds__(256)
void k_main(const float* __restrict__ x,
            const float* __restrict__ gprm,
            const float* __restrict__ g_scale, const float* __restrict__ g_shift,
            float* __restrict__ out) {
    __shared__ float xl[SEQ], scl[SEQ], shl[SEQ];
    __shared__ float po[SEQ];
    __shared__ float2 aggA[4][PP], aggS[4][PP];
    const int tid = threadIdx.x, b = blockIdx.x;
    for (int i = tid; i < SEQ; i += 256) {
        xl[i] = x[(size_t)b * SEQ + i];
        scl[i] = g_scale[i];
        shl[i] = g_shift[i];
    }
    __syncthreads();
    const float4* g0v  = (const float4*)(gprm + O_G0);
    const float4* h0v  = (const float4*)(gprm + O_H0);
    const float4* c0v  = (const float4*)(gprm + O_C0V);
    const float4* f0v  = (const float4*)(gprm + O_F0);
    const float4* g1v  = (const float4*)(gprm + O_G1);
    const float4* g2v  = (const float4*)(gprm + O_G2);
    const float4* h12v = (const float4*)(gprm + O_H12);
    const float4* c1v  = (const float4*)(gprm + O_C1V);
    const float4* bb1  = (const float4*)(gprm + O_BB1);
    const float4* bb2  = (const float4*)(gprm + O_BB2);
    const float4* f1v  = (const float4*)(gprm + O_F1);
    const float2* cwv  = (const float2*)(gprm + O_CW);
    const float Sc0 = gprm[O_SC], Sc1 = gprm[O_SC + 1];
    const int w = tid >> 6, lane = tid & 63;
    const int len = (w == 3) ? 7 : 6;
    const int l0 = (w < 3) ? (w * 384 + lane * 6) : (1152 + lane * 7);
    const float2* aLb = (const float2*)(gprm + ((w == 3) ? O_A7 : O_A6));
    const float2* aL0 = aLb;
    const float2* aL1 = aLb + 1 * PP;
    const float2* aL2 = aLb + 2 * PP;

    float s0r[PP], s0i[PP];
    float car0r[PP], car0i[PP];

    // ================= pass A: layer-0 local scan =================
#pragma unroll
    for (int p = 0; p < PP; p++) { s0r[p] = 0.f; s0i[p] = 0.f; }
#pragma unroll 1
    for (int j = 0; j < len; j++) {
        int l = l0 + j;
        float xx = xl[l], sc = scl[l], sh = shl[l];
        float xs = xx * sc;
#pragma unroll
        for (int p = 0; p < PP; p++) {
            float4 g = g0v[p]; float4 hv = h0v[p];
            float bur = xs * g.x + sc * g.z + sh * hv.x;
            float bui = xs * g.y + sc * g.w + sh * hv.y;
            float nr = hv.z * s0r[p] - hv.w * s0i[p] + bur;
            float ni = hv.z * s0i[p] + hv.w * s0r[p] + bui;
            s0r[p] = nr; s0i[p] = ni;
        }
    }
    scan_carry256(s0r, s0i, aL0, lane, w, aggA, aggS);
#pragma unroll
    for (int p = 0; p < PP; p++) { car0r[p] = s0r[p]; car0i[p] = s0i[p]; }

    // ================= pass B: layer-0 exact + layer-1 local =================
    float s1r[PP], s1i[PP];
#pragma unroll
    for (int p = 0; p < PP; p++) { s1r[p] = 0.f; s1i[p] = 0.f; }
#pragma unroll 1
    for (int j = 0; j < len; j++) {
        int l = l0 + j;
        float xx = xl[l], sc = scl[l], sh = shl[l];
        float xs = xx * sc;
#pragma unroll
        for (int p = 0; p < PP; p++) {
            float4 g = g0v[p]; float4 hv = h0v[p];
            float bur = xs * g.x + sc * g.z + sh * hv.x;
            float bui = xs * g.y + sc * g.w + sh * hv.y;
            float nr = hv.z * s0r[p] - hv.w * s0i[p] + bur;
            float ni = hv.z * s0i[p] + hv.w * s0r[p] + bui;
            s0r[p] = nr; s0i[p] = ni;
        }
        float r0v[H];
#pragma unroll
        for (int h = 0; h < H; h++) {
            float acc = 0.f;
#pragma unroll
            for (int k = 0; k < 4; k++) {
                float4 v = c0v[h * 4 + k];
                acc += s0r[2 * k] * v.x - s0i[2 * k] * v.y + s0r[2 * k + 1] * v.z - s0i[2 * k + 1] * v.w;
            }
            float4 f = f0v[h];
            float y0 = 2.f * acc + xs * f.x + sc * f.y + sh * f.z;
            r0v[h] = fmaxf(y0, 0.f);
        }
        float t1r[PP], t1i[PP];
#pragma unroll
        for (int p = 0; p < PP; p++) {
            float4 g = g1v[p];
            t1r[p] = xx * g.x + g.z; t1i[p] = xx * g.y + g.w;
        }
#pragma unroll
        for (int h = 0; h < H; h++) {
            float rh = r0v[h];
#pragma unroll
            for (int k = 0; k < 4; k++) {
                float4 v = bb1[h * 4 + k];
                t1r[2 * k] += rh * v.x; t1i[2 * k] += rh * v.y;
                t1r[2 * k + 1] += rh * v.z; t1i[2 * k + 1] += rh * v.w;
            }
        }
#pragma unroll
        for (int p = 0; p < PP; p++) {
            float4 hv = h12v[p];
            float nr = hv.x * s1r[p] - hv.y * s1i[p] + t1r[p];
            float ni = hv.x * s1i[p] + hv.y * s1r[p] + t1i[p];
            s1r[p] = nr; s1i[p] = ni;
        }
    }
    scan_carry256(s1r, s1i, aL1, lane, w, aggA, aggS);

    // ================= pass C: L0 exact + L1 exact + L2 local + partial out =================
    float s2r[PP], s2i[PP];
#pragma unroll
    for (int p = 0; p < PP; p++) {
        s0r[p] = car0r[p]; s0i[p] = car0i[p];
        s2r[p] = 0.f;      s2i[p] = 0.f;
    }
#pragma unroll 1
    for (int j = 0; j < len; j++) {
        int l = l0 + j;
        float xx = xl[l], sc = scl[l], sh = shl[l];
        float xs = xx * sc;
#pragma unroll
        for (int p = 0; p < PP; p++) {
            float4 g = g0v[p]; float4 hv = h0v[p];
            float bur = xs * g.x + sc * g.z + sh * hv.x;
            float bui = xs * g.y + sc * g.w + sh * hv.y;
            float nr = hv.z * s0r[p] - hv.w * s0i[p] + bur;
            float ni = hv.z * s0i[p] + hv.w * s0r[p] + bui;
            s0r[p] = nr; s0i[p] = ni;
        }
        float r0v[H];
#pragma unroll
        for (int h = 0; h < H; h++) {
            float acc = 0.f;
#pragma unroll
            for (int k = 0; k < 4; k++) {
                float4 v = c0v[h * 4 + k];
                acc += s0r[2 * k] * v.x - s0i[2 * k] * v.y + s0r[2 * k + 1] * v.z - s0i[2 * k + 1] * v.w;
            }
            float4 f = f0v[h];
            float y0 = 2.f * acc + xs * f.x + sc * f.y + sh * f.z;
            r0v[h] = fmaxf(y0, 0.f);
        }
        float t1r[PP], t1i[PP];
#pragma unroll
        for (int p = 0; p < PP; p++) {
            float4 g = g1v[p];
            t1r[p] = xx * g.x + g.z; t1i[p] = xx * g.y + g.w;
        }
#pragma unroll
        for (int h = 0; h < H; h++) {
            float rh = r0v[h];
#pragma unroll
            for (int k = 0; k < 4; k++) {
                float4 v = bb1[h * 4 + k];
                t1r[2 * k] += rh * v.x; t1i[2 * k] += rh * v.y;
                t1r[2 * k + 1] += rh * v.z; t1i[2 * k + 1] += rh * v.w;
            }
        }
#pragma unroll
        for (int p = 0; p < PP; p++) {
            float4 hv = h12v[p];
            float nr = hv.x * s1r[p] - hv.y * s1i[p] + t1r[p];
            float ni = hv.x * s1i[p] + hv.y * s1r[p] + t1i[p];
            s1r[p] = nr; s1i[p] = ni;
        }
        // layer-2 local recurrence consuming rs = r0 + relu(y1) straight from regs
        float t2r[PP], t2i[PP];
#pragma unroll
        for (int p = 0; p < PP; p++) {
            float4 g = g2v[p];
            t2r[p] = xx * g.x + g.z; t2i[p] = xx * g.y + g.w;
        }
        float o = Sc0 + xx * Sc1;
#pragma unroll
        for (int h = 0; h < H; h++) {
            float acc = 0.f;
#pragma unroll
            for (int k = 0; k < 4; k++) {
                float4 v = c1v[h * 4 + k];
                acc += s1r[2 * k] * v.x - s1i[2 * k] * v.y + s1r[2 * k + 1] * v.z - s1i[2 * k + 1] * v.w;
            }
            float4 f = f1v[h];
            float y1 = 2.f * acc + r0v[h] * f.y + xx * f0v[h].w + f.x;
            float rs = r0v[h] + fmaxf(y1, 0.f);
            o += rs * f.z;
#pragma unroll
            for (int k = 0; k < 4; k++) {
                float4 v = bb2[h * 4 + k];
                t2r[2 * k] += rs * v.x; t2i[2 * k] += rs * v.y;
                t2r[2 * k + 1] += rs * v.z; t2i[2 * k + 1] += rs * v.w;
            }
        }
#pragma unroll
        for (int p = 0; p < PP; p++) {
            float4 hv = h12v[p];
            float nr = hv.z * s2r[p] - hv.w * s2i[p] + t2r[p];
            float ni = hv.z * s2i[p] + hv.w * s2r[p] + t2i[p];
            s2r[p] = nr; s2i[p] = ni;
        }
        float acc2 = 0.f;
#pragma unroll
        for (int p = 0; p < PP; p++) {
            float2 c = cwv[p];
            acc2 += s2r[p] * c.x - s2i[p] * c.y;
        }
        po[l] = o + 2.f * acc2;   // partial (zero layer-2 carry)
    }
    scan_carry256(s2r, s2i, aL2, lane, w, aggA, aggS);  // -> carry2

    // fixup: += 2*Re(lam2^{j+1} * carry2 . cw)
    float tr[PP], ti_[PP], mr[PP], mi_[PP];
#pragma unroll
    for (int p = 0; p < PP; p++) {
        float2 c = cwv[p];
        tr[p]  = c.x * s2r[p] - c.y * s2i[p];
        ti_[p] = c.x * s2i[p] + c.y * s2r[p];
        float4 hv = h12v[p];
        mr[p] = hv.z; mi_[p] = hv.w;
    }
#pragma unroll 1
    for (int j = 0; j < len; j++) {
        float corr = 0.f;
#pragma unroll
        for (int p = 0; p < PP; p++) corr += mr[p] * tr[p] - mi_[p] * ti_[p];
        po[l0 + j] += 2.f * corr;
#pragma unroll
        for (int p = 0; p < PP; p++) {
            float4 hv = h12v[p];
            float t = mr[p] * hv.z - mi_[p] * hv.w;
            mi_[p] = mr[p] * hv.w + mi_[p] * hv.z;
            mr[p] = t;
        }
    }
    __syncthreads();
    float* orow = out + (size_t)b * SEQ;
    for (int i = tid; i < SEQ; i += 256) orow[i] = po[i];
}

extern "C" void kernel_launch(void* const* d_in, const int* in_sizes, int n_in,
                              void* d_out, int out_size, void* d_ws, size_t ws_size,
                              hipStream_t stream) {
    const float* x     = (const float*)d_in[0];
    const float* l1w   = (const float*)d_in[1];
    const float* l1b   = (const float*)d_in[2];
    const float* l2w   = (const float*)d_in[3];
    const float* l2b   = (const float*)d_in[4];
    const float* gam   = (const float*)d_in[5];
    const float* bet   = (const float*)d_in[6];
    const float* lamr  = (const float*)d_in[7];
    const float* lami  = (const float*)d_in[8];
    const float* bre   = (const float*)d_in[9];
    const float* bim   = (const float*)d_in[10];
    const float* cre   = (const float*)d_in[11];
    const float* cim   = (const float*)d_in[12];
    const float* dv    = (const float*)d_in[13];
    const float* lstep = (const float*)d_in[14];
    float* out = (float*)d_out;

    float* wsf     = (float*)d_ws;
    float* w_scale = wsf;                  // 1600
    float* w_shift = wsf + SEQ;            // 1600
    float* pS      = wsf + 2 * SEQ;        // 16*1600
    float* pQ      = pS + 16 * SEQ;        // 16*1600
    float* gprm    = pQ + 16 * SEQ;        // PRMF (padded to 1280)

    k_prep<<<dim3(1), 64, 0, stream>>>(l1w, l1b, l2w, l2b, lamr, lami,
                                       bre, bim, cre, cim, dv, lstep, gprm);
    k_stats1<<<dim3(7, 16), 256, 0, stream>>>(x, pS, pQ);
    k_stats2<<<dim3(7), 256, 0, stream>>>(pS, pQ, l1w, l1b, gam, bet, w_scale, w_shift);
    k_main<<<dim3(NB), 256, 0, stream>>>(x, gprm, w_scale, w_shift, out);
}